// Round 4
// baseline (638.699 us; speedup 1.0000x reference)
//
#include <hip/hip_runtime.h>

typedef _Float16 half_t;
typedef _Float16 half8 __attribute__((ext_vector_type(8)));
typedef float f32x4 __attribute__((ext_vector_type(4)));

// dims: T=64 B=32 V=32000 E=512 H=512 N=512 DK=256 DV=512, TB=2048

__device__ __forceinline__ void gload_lds16(const void* g, void* l) {
  __builtin_amdgcn_global_load_lds((const __attribute__((address_space(1))) void*)g,
                                   (__attribute__((address_space(3))) void*)l, 16, 0, 0);
}

// ---------------- Wout [512,32000] f32 -> WoutT [32000,512] f16 ----------------
__global__ __launch_bounds__(256) void kConvT(const float* __restrict__ Wout,
                                              half_t* __restrict__ WoutT) {
  __shared__ half_t tile[64][68];  // [n][k], pad 68
  int n0 = blockIdx.x * 64, k0 = blockIdx.y * 64;
  for (int p = 0; p < 4; p++) {
    int id = p * 256 + threadIdx.x;
    int k = id >> 4, nq = id & 15;
    float4 v = *(const float4*)&Wout[(size_t)(k0 + k) * 32000 + n0 + nq * 4];
    tile[nq * 4 + 0][k] = (half_t)v.x; tile[nq * 4 + 1][k] = (half_t)v.y;
    tile[nq * 4 + 2][k] = (half_t)v.z; tile[nq * 4 + 3][k] = (half_t)v.w;
  }
  __syncthreads();
  for (int p = 0; p < 2; p++) {
    int id = p * 256 + threadIdx.x;
    int n = id >> 3, kc = id & 7;
    half8 h = *(const half8*)&tile[n][kc * 8];
    *(half8*)&WoutT[(size_t)(n0 + n) * 512 + k0 + kc * 8] = h;
  }
}

// ---------------- Wh [1024,512] f32 -> W1T/W2T [512][512] f16 (transposed) ------
__global__ __launch_bounds__(256) void kWhT(const float* __restrict__ Wh,
                                            half_t* __restrict__ W1T,
                                            half_t* __restrict__ W2T) {
  __shared__ half_t tile[64][66];
  int n0 = blockIdx.x * 64, k0 = blockIdx.y * 64;
  for (int p = 0; p < 16; p++) {
    int id = p * 256 + threadIdx.x;
    int kk = id >> 6, nn = id & 63;
    tile[nn][kk] = (half_t)Wh[(size_t)(k0 + kk) * 512 + n0 + nn];
  }
  __syncthreads();
  half_t* out = (k0 < 512) ? W1T : W2T;
  int kb = k0 & 511;
  for (int p = 0; p < 16; p++) {
    int id = p * 256 + threadIdx.x;
    int nn = id >> 6, kk = id & 63;
    out[(size_t)(n0 + nn) * 512 + kb + kk] = tile[nn][kk];
  }
}

// ---------------- X gather + f16 copy + per-t mean (fp64) ----------------
__global__ __launch_bounds__(256) void kGatherXM(const int* __restrict__ tok,
                                                 const float* __restrict__ emb,
                                                 float* __restrict__ X,
                                                 half_t* __restrict__ Xh,
                                                 double* __restrict__ XM) {
  int t = blockIdx.x, c = threadIdx.x;
  double s0 = 0.0, s1 = 0.0;
  for (int b = 0; b < 32; b++) {
    int row = t * 32 + b;
    const float* src = emb + (size_t)tok[row] * 512;
    float v0 = src[c], v1 = src[c + 256];
    X[(size_t)row * 512 + c] = v0; X[(size_t)row * 512 + c + 256] = v1;
    Xh[(size_t)row * 512 + c] = (half_t)v0; Xh[(size_t)row * 512 + c + 256] = (half_t)v1;
    s0 += (double)v0; s1 += (double)v1;
  }
  XM[(size_t)t * 512 + c] = s0 * (1.0 / 32.0);
  XM[(size_t)t * 512 + c + 256] = s1 * (1.0 / 32.0);
}

// ---------------- Q = X @ Wq (double accum), 4 rows per WG ----------------
__global__ __launch_bounds__(256) void kQ(const float* __restrict__ X,
                                          const float* __restrict__ Wq,
                                          double* __restrict__ Q) {
  __shared__ float xs[4][512];
  int r0 = blockIdx.x * 4;
  for (int p = 0; p < 8; p++) {
    int id = p * 256 + threadIdx.x;
    int r = id >> 9, i = id & 511;
    xs[r][i] = X[(size_t)(r0 + r) * 512 + i];
  }
  __syncthreads();
  int d = threadIdx.x;
  double a0 = 0, a1 = 0, a2 = 0, a3 = 0;
  #pragma unroll 4
  for (int i = 0; i < 512; i++) {
    double w = (double)Wq[(size_t)i * 256 + d];
    a0 += (double)xs[0][i] * w; a1 += (double)xs[1][i] * w;
    a2 += (double)xs[2][i] * w; a3 += (double)xs[3][i] * w;
  }
  Q[(size_t)(r0 + 0) * 256 + d] = a0; Q[(size_t)(r0 + 1) * 256 + d] = a1;
  Q[(size_t)(r0 + 2) * 256 + d] = a2; Q[(size_t)(r0 + 3) * 256 + d] = a3;
}

// ---------------- NK = Xmean @ Wk (double) ----------------
__global__ __launch_bounds__(256) void kNK(const double* __restrict__ XM,
                                           const float* __restrict__ Wk,
                                           double* __restrict__ NK) {
  __shared__ double xm[512];
  int t = blockIdx.x;
  for (int i = threadIdx.x; i < 512; i += 256) xm[i] = XM[(size_t)t * 512 + i];
  __syncthreads();
  int d = threadIdx.x;
  double a = 0;
  #pragma unroll 4
  for (int i = 0; i < 512; i++) a += xm[i] * (double)Wk[(size_t)i * 256 + d];
  NK[(size_t)t * 256 + d] = a;
}

// ---------------- scores (fp64 accum, LDS-staged keys) + top-8 + softmax -------
__global__ __launch_bounds__(512) void kScoreTopk(const double* __restrict__ Qm,
                                                  const double* __restrict__ NKm,
                                                  const float* __restrict__ keys0,
                                                  float* __restrict__ WSo,
                                                  int* __restrict__ ISo) {
  __shared__ double qs[4][256];
  __shared__ float kb[64][257];
  __shared__ double sb[4][512];
  int t = blockIdx.x >> 3, bq = blockIdx.x & 7;
  int r0 = t * 32 + bq * 4;
  for (int id = threadIdx.x; id < 1024; id += 512) {
    int r = id >> 8, d = id & 255;
    qs[r][d] = Qm[(size_t)(r0 + r) * 256 + d];
  }
  for (int c = 0; c < 8; c++) {
    __syncthreads();
    // stage keys rows c*64 .. c*64+63 into LDS (coalesced)
    for (int jj = 0; jj < 32; jj++) {
      int idx = jj * 512 + threadIdx.x;
      int rr = idx >> 8, d = idx & 255;
      int n = c * 64 + rr;
      kb[rr][d] = (n < t) ? (float)NKm[(size_t)n * 256 + d]
                          : keys0[(size_t)n * 256 + d];
    }
    __syncthreads();
    if (threadIdx.x < 256) {
      int r = threadIdx.x >> 6, nl = threadIdx.x & 63;
      const float* kr = kb[nl];
      double a = 0;
      #pragma unroll 4
      for (int d = 0; d < 256; d++) a += qs[r][d] * (double)kr[d];
      sb[r][c * 64 + nl] = a * 0.0625;
    }
  }
  __syncthreads();
  int wv = threadIdx.x >> 6, lane = threadIdx.x & 63;
  if (wv < 4) {
    double topv[8]; int topi[8];
    for (int it = 0; it < 8; it++) {
      double bvv = -1e300; int bii = 0x7fffffff;
      #pragma unroll
      for (int j = 0; j < 8; j++) {
        int ii = lane + 64 * j;
        double vvv = sb[wv][ii];
        if (vvv > bvv || (vvv == bvv && ii < bii)) { bvv = vvv; bii = ii; }
      }
      #pragma unroll
      for (int s = 32; s > 0; s >>= 1) {
        double ov = __shfl_xor(bvv, s, 64);
        int oi = __shfl_xor(bii, s, 64);
        if (ov > bvv || (ov == bvv && oi < bii)) { bvv = ov; bii = oi; }
      }
      topv[it] = bvv; topi[it] = bii;
      if (lane == 0) sb[wv][bii] = -1e300;
      asm volatile("s_waitcnt lgkmcnt(0)" ::: "memory");
    }
    if (lane == 0) {
      double m = topv[0], ev[8], Z = 0;
      #pragma unroll
      for (int i2 = 0; i2 < 8; i2++) { ev[i2] = exp(topv[i2] - m); Z += ev[i2]; }
      double inv = 1.0 / Z;
      #pragma unroll
      for (int i2 = 0; i2 < 8; i2++) {
        WSo[(size_t)(r0 + wv) * 8 + i2] = (float)(ev[i2] * inv);
        ISo[(size_t)(r0 + wv) * 8 + i2] = topi[i2];
      }
    }
  }
}

// ---------------- fast-path retrieved -> fp16; + DEP flags + bars zero ---------
__global__ __launch_bounds__(256) void kRetrDeps(const float* __restrict__ vals0,
                                                 const float* __restrict__ WSo,
                                                 const int* __restrict__ ISo,
                                                 half_t* __restrict__ R16,
                                                 int* __restrict__ DEP,
                                                 int* __restrict__ bars) {
  int bid = blockIdx.x;
  if (bid >= 2048) {  // kDeps role
    int t = bid - 2048;
    __shared__ int f;
    if (threadIdx.x == 0) f = 0;
    __syncthreads();
    int idx = ISo[(size_t)t * 256 + threadIdx.x];
    if (idx < t) atomicOr(&f, 1);
    __syncthreads();
    if (threadIdx.x == 0) DEP[t] = f;
    if (t == 0) bars[threadIdx.x] = 0;
    return;
  }
  __shared__ float wl[8];
  __shared__ int il[8];
  int row = bid;
  if (threadIdx.x < 8) {
    wl[threadIdx.x] = WSo[(size_t)row * 8 + threadIdx.x];
    il[threadIdx.x] = ISo[(size_t)row * 8 + threadIdx.x];
  }
  __syncthreads();
  int c = threadIdx.x;
  float a0 = 0.f, a1 = 0.f;
  #pragma unroll
  for (int k2 = 0; k2 < 8; k2++) {
    const float* src = vals0 + (size_t)il[k2] * 512;
    a0 += wl[k2] * src[c];
    a1 += wl[k2] * src[c + 256];
  }
  R16[(size_t)row * 512 + c] = (half_t)a0;
  R16[(size_t)row * 512 + c + 256] = (half_t)a1;
}

// ------- fused: acc = Xh@W1T^T (write XH+bh) + R16@W2T^T; HH=tanh(acc+bh); HM --
__global__ __launch_bounds__(256) void kFused(const half_t* __restrict__ Xh,
                                              const half_t* __restrict__ R16,
                                              const half_t* __restrict__ W1T,
                                              const half_t* __restrict__ W2T,
                                              const float* __restrict__ bh,
                                              float* __restrict__ XH,
                                              half_t* __restrict__ HH,
                                              float* __restrict__ HM) {
  __shared__ half_t lA[128 * 32];
  __shared__ half_t lB[128 * 32];
  int n0 = blockIdx.x * 128, m0 = blockIdx.y * 128;
  int tid = threadIdx.x, wid = tid >> 6, lane = tid & 63;
  int wm = wid >> 1, wn = wid & 1;
  f32x4 acc[4][4];
  #pragma unroll
  for (int a2 = 0; a2 < 4; a2++)
    #pragma unroll
    for (int b2 = 0; b2 < 4; b2++) acc[a2][b2] = (f32x4){0.f, 0.f, 0.f, 0.f};
  int rA = lane >> 2;
  int cswz = ((lane & 3) ^ ((lane >> 3) & 3)) * 8;       // source pre-swizzle
  int koffs = (((lane >> 4) ^ ((lane >> 1) & 3))) * 8;   // swizzled read offset
  for (int kt = 0; kt < 32; kt++) {
    const half_t* Ap = (kt < 16) ? Xh : R16;
    const half_t* Bp = (kt < 16) ? W1T : W2T;
    int kk = kt & 15;
    __syncthreads();
    #pragma unroll
    for (int i2 = 0; i2 < 2; i2++) {
      int blk = wid * 2 + i2;
      gload_lds16(Ap + ((size_t)(m0 + blk * 16 + rA) * 512 + kk * 32 + cswz), (void*)(lA + blk * 512));
      gload_lds16(Bp + ((size_t)(n0 + blk * 16 + rA) * 512 + kk * 32 + cswz), (void*)(lB + blk * 512));
    }
    asm volatile("s_waitcnt vmcnt(0)" ::: "memory");
    __syncthreads();
    half8 af[4], bf[4];
    #pragma unroll
    for (int mf = 0; mf < 4; mf++)
      af[mf] = *(const half8*)&lA[(wm * 64 + mf * 16 + (lane & 15)) * 32 + koffs];
    #pragma unroll
    for (int nf = 0; nf < 4; nf++)
      bf[nf] = *(const half8*)&lB[(wn * 64 + nf * 16 + (lane & 15)) * 32 + koffs];
    #pragma unroll
    for (int mf = 0; mf < 4; mf++)
      #pragma unroll
      for (int nf = 0; nf < 4; nf++)
        acc[mf][nf] = __builtin_amdgcn_mfma_f32_16x16x32_f16(af[mf], bf[nf], acc[mf][nf], 0, 0, 0);
    if (kt == 15) {  // acc == Xh@W1T^T : persist XH (+bias) for the fixup path
      #pragma unroll
      for (int nf = 0; nf < 4; nf++) {
        int col = n0 + wn * 64 + nf * 16 + (lane & 15);
        float bv = bh[col];
        #pragma unroll
        for (int mf = 0; mf < 4; mf++) {
          int rbase = m0 + wm * 64 + mf * 16 + (lane >> 4) * 4;
          #pragma unroll
          for (int r = 0; r < 4; r++)
            XH[(size_t)(rbase + r) * 512 + col] = acc[mf][nf][r] + bv;
        }
      }
    }
  }
  // epilogue: tanh + HH write + per-t column means (t = 32 rows = 2 mf blocks)
  #pragma unroll
  for (int tt = 0; tt < 2; tt++) {
    #pragma unroll
    for (int nf = 0; nf < 4; nf++) {
      int col = n0 + wn * 64 + nf * 16 + (lane & 15);
      float bv = bh[col];
      float cs = 0.f;
      #pragma unroll
      for (int mfp = 0; mfp < 2; mfp++) {
        int mf = tt * 2 + mfp;
        int rbase = m0 + wm * 64 + mf * 16 + (lane >> 4) * 4;
        #pragma unroll
        for (int r = 0; r < 4; r++) {
          float v = tanhf(acc[mf][nf][r] + bv);
          HH[(size_t)(rbase + r) * 512 + col] = (half_t)v;
          cs += v;
        }
      }
      cs += __shfl_xor(cs, 16, 64);
      cs += __shfl_xor(cs, 32, 64);
      if ((lane >> 4) == 0) {
        int t = (m0 >> 5) + wm * 2 + tt;
        HM[(size_t)t * 512 + col] = cs * (1.f / 32.f);
      }
    }
  }
}

// ---------------- NV[t] = hmean[t] @ Wv ----------------
__global__ __launch_bounds__(256) void kNVall(const float* __restrict__ HMm,
                                              const float* __restrict__ Wv,
                                              float* __restrict__ NV) {
  __shared__ float hm[512];
  int t = blockIdx.x;
  hm[threadIdx.x] = HMm[(size_t)t * 512 + threadIdx.x];
  hm[threadIdx.x + 256] = HMm[(size_t)t * 512 + threadIdx.x + 256];
  __syncthreads();
  for (int v = threadIdx.x; v < 512; v += 256) {
    float a = 0.f;
    #pragma unroll 4
    for (int i = 0; i < 512; i++) a += hm[i] * Wv[(size_t)i * 512 + v];
    NV[(size_t)t * 512 + v] = a;
  }
}

// ---------------- grid barrier (64 resident WGs) ----------------
__device__ __forceinline__ void gbar(int* bars, int id, int nwg) {
  __syncthreads();
  if (threadIdx.x == 0) {
    __hip_atomic_fetch_add(&bars[id], 1, __ATOMIC_ACQ_REL, __HIP_MEMORY_SCOPE_AGENT);
    while (__hip_atomic_load(&bars[id], __ATOMIC_ACQUIRE, __HIP_MEMORY_SCOPE_AGENT) < nwg)
      __builtin_amdgcn_s_sleep(4);
  }
  __syncthreads();
}

// ---------------- sequential fixup for steps that selected generated slots -----
__global__ __launch_bounds__(256) void kFixup(const int* __restrict__ DEP,
                                              int* __restrict__ bars,
                                              const float* __restrict__ XHm,
                                              const float* __restrict__ Wh,
                                              const float* __restrict__ Wv,
                                              const float* __restrict__ vals0,
                                              const float* __restrict__ WSo,
                                              const int* __restrict__ ISo,
                                              float* __restrict__ NV,
                                              float* __restrict__ RETR,
                                              float* __restrict__ HB,
                                              half_t* __restrict__ HHm) {
  __shared__ float rl[512];
  __shared__ float hm2[512];
  int w = blockIdx.x;
  int barid = 0;
  for (int t = 0; t < 64; t++) {
    if (DEP[t] == 0) continue;
    {  // phase A: retrieved with NV for idx<t
      int b = w >> 1, hf = w & 1;
      int c = hf * 256 + threadIdx.x;
      int row = t * 32 + b;
      float acc = 0.f;
      #pragma unroll
      for (int k2 = 0; k2 < 8; k2++) {
        int idx = ISo[(size_t)row * 8 + k2];
        float wv2 = WSo[(size_t)row * 8 + k2];
        const float* src = (idx < t) ? (NV + (size_t)idx * 512) : (vals0 + (size_t)idx * 512);
        acc += wv2 * src[c];
      }
      RETR[(size_t)b * 512 + c] = acc;
    }
    gbar(bars, barid++, 64);
    if (w < 32) {  // phase B: h row b
      int b = w;
      rl[threadIdx.x] = RETR[(size_t)b * 512 + threadIdx.x];
      rl[threadIdx.x + 256] = RETR[(size_t)b * 512 + threadIdx.x + 256];
      __syncthreads();
      int row = t * 32 + b;
      for (int cc = 0; cc < 2; cc++) {
        int col = cc * 256 + threadIdx.x;
        float acc = 0.f;
        #pragma unroll 4
        for (int i = 0; i < 512; i++) acc += rl[i] * Wh[(size_t)(512 + i) * 512 + col];
        float h = tanhf(XHm[(size_t)row * 512 + col] + acc);
        HB[(size_t)b * 512 + col] = h;
        HHm[(size_t)row * 512 + col] = (half_t)h;
      }
    }
    gbar(bars, barid++, 64);
    if (w == 0) {  // phase C: hmean + NV[t]
      for (int j = threadIdx.x; j < 512; j += 256) {
        float s = 0.f;
        for (int b = 0; b < 32; b++) s += HB[(size_t)b * 512 + j];
        hm2[j] = s * (1.f / 32.f);
      }
      __syncthreads();
      for (int v = threadIdx.x; v < 512; v += 256) {
        float a = 0.f;
        #pragma unroll 4
        for (int i = 0; i < 512; i++) a += hm2[i] * Wv[(size_t)i * 512 + v];
        NV[(size_t)t * 512 + v] = a;
      }
    }
    gbar(bars, barid++, 64);
  }
}

// ---------------- logits = HH @ WoutT^T + bout  (fp16 MFMA, swizzled LDS) ------
__global__ __launch_bounds__(256) void kLogits(const half_t* __restrict__ A,
                                               const half_t* __restrict__ Bm,
                                               const float* __restrict__ bout,
                                               float* __restrict__ C) {
  __shared__ half_t lA[128 * 32];
  __shared__ half_t lB[128 * 32];
  // XCD-aware bijective remap: 4000 WGs, 8 XCDs, n-major so each XCD owns a
  // contiguous ~31-n-tile slab (B-chunk ~4MB fits per-XCD L2).
  int lin = blockIdx.y * 250 + blockIdx.x;
  int swz = (lin & 7) * 500 + (lin >> 3);
  int m0 = (swz & 15) * 128;
  int n0 = (swz >> 4) * 128;
  int tid = threadIdx.x, wid = tid >> 6, lane = tid & 63;
  int wm = wid >> 1, wn = wid & 1;
  f32x4 acc[4][4];
  #pragma unroll
  for (int a2 = 0; a2 < 4; a2++)
    #pragma unroll
    for (int b2 = 0; b2 < 4; b2++) acc[a2][b2] = (f32x4){0.f, 0.f, 0.f, 0.f};

  int rA = lane >> 2;
  int cswz = ((lane & 3) ^ ((lane >> 3) & 3)) * 8;
  int koffs = (((lane >> 4) ^ ((lane >> 1) & 3))) * 8;
  for (int kt = 0; kt < 16; kt++) {
    __syncthreads();
    #pragma unroll
    for (int i2 = 0; i2 < 2; i2++) {
      int blk = wid * 2 + i2;
      gload_lds16(A + ((size_t)(m0 + blk * 16 + rA) * 512 + kt * 32 + cswz), (void*)(lA + blk * 512));
      gload_lds16(Bm + ((size_t)(n0 + blk * 16 + rA) * 512 + kt * 32 + cswz), (void*)(lB + blk * 512));
    }
    asm volatile("s_waitcnt vmcnt(0)" ::: "memory");
    __syncthreads();
    half8 af[4], bf[4];
    #pragma unroll
    for (int mf = 0; mf < 4; mf++)
      af[mf] = *(const half8*)&lA[(wm * 64 + mf * 16 + (lane & 15)) * 32 + koffs];
    #pragma unroll
    for (int nf = 0; nf < 4; nf++)
      bf[nf] = *(const half8*)&lB[(wn * 64 + nf * 16 + (lane & 15)) * 32 + koffs];
    #pragma unroll
    for (int mf = 0; mf < 4; mf++)
      #pragma unroll
      for (int nf = 0; nf < 4; nf++)
        acc[mf][nf] = __builtin_amdgcn_mfma_f32_16x16x32_f16(af[mf], bf[nf], acc[mf][nf], 0, 0, 0);
  }
  #pragma unroll
  for (int nf = 0; nf < 4; nf++) {
    int col = n0 + wn * 64 + nf * 16 + (lane & 15);
    float bv = bout[col];
    #pragma unroll
    for (int mf = 0; mf < 4; mf++) {
      int rbase = m0 + wm * 64 + mf * 16 + (lane >> 4) * 4;
      #pragma unroll
      for (int r = 0; r < 4; r++)
        C[(size_t)(rbase + r) * 32000 + col] = acc[mf][nf][r] + bv;
    }
  }
}

extern "C" void kernel_launch(void* const* d_in, const int* in_sizes, int n_in,
                              void* d_out, int out_size, void* d_ws, size_t ws_size,
                              hipStream_t stream) {
  (void)in_sizes; (void)n_in; (void)out_size; (void)ws_size;
  const int*   tok   = (const int*)d_in[0];
  const float* emb   = (const float*)d_in[1];
  const float* Wq    = (const float*)d_in[2];
  const float* Wk    = (const float*)d_in[3];
  const float* Wv    = (const float*)d_in[4];
  const float* Wh    = (const float*)d_in[5];
  const float* bh    = (const float*)d_in[6];
  const float* Wout  = (const float*)d_in[7];
  const float* bout  = (const float*)d_in[8];
  const float* keys0 = (const float*)d_in[9];
  const float* vals0 = (const float*)d_in[10];
  float* Cout = (float*)d_out;

  char* ws = (char*)d_ws;
  size_t off = 0;
  auto alloc = [&](size_t bytes) -> char* {
    char* p = ws + off;
    off += (bytes + 255) & ~(size_t)255;
    return p;
  };
  half_t* WoutT = (half_t*)alloc(32768000);  // [32000][512] f16
  half_t* W1T   = (half_t*)alloc(524288);    // [512][512] f16
  half_t* W2T   = (half_t*)alloc(524288);    // [512][512] f16
  float*  X     = (float*) alloc(4194304);   // [2048][512]
  half_t* Xh    = (half_t*)alloc(2097152);   // [2048][512] f16
  double* Qd    = (double*)alloc(4194304);   // [2048][256]
  double* NKd   = (double*)alloc(131072);    // [64][256]
  double* XM    = (double*)alloc(262144);    // [64][512]
  float*  XH    = (float*) alloc(4194304);   // [2048][512]
  float*  WSb   = (float*) alloc(65536);     // [2048][8]
  int*    ISb   = (int*)   alloc(65536);     // [2048][8]
  float*  NV    = (float*) alloc(131072);    // [64][512]
  half_t* R16   = (half_t*)alloc(2097152);   // [2048][512] f16
  half_t* HH    = (half_t*)alloc(2097152);   // [2048][512]
  float*  HM    = (float*) alloc(131072);    // [64][512]
  float*  RETR  = (float*) alloc(65536);     // [32][512]
  float*  HB    = (float*) alloc(65536);     // [32][512]
  int*    DEP   = (int*)   alloc(256);       // [64]
  int*    bars  = (int*)   alloc(1024);      // [256]

  kConvT<<<dim3(500, 8), 256, 0, stream>>>(Wout, WoutT);
  kWhT<<<dim3(8, 16), 256, 0, stream>>>(Wh, W1T, W2T);
  kGatherXM<<<64, 256, 0, stream>>>(tok, emb, X, Xh, XM);
  kQ<<<512, 256, 0, stream>>>(X, Wq, Qd);
  kNK<<<64, 256, 0, stream>>>(XM, Wk, NKd);
  kScoreTopk<<<512, 512, 0, stream>>>(Qd, NKd, keys0, WSb, ISb);
  kRetrDeps<<<2112, 256, 0, stream>>>(vals0, WSb, ISb, R16, DEP, bars);
  kFused<<<dim3(4, 16), 256, 0, stream>>>(Xh, R16, W1T, W2T, bh, XH, HH, HM);
  kNVall<<<64, 256, 0, stream>>>(HM, Wv, NV);
  kFixup<<<64, 256, 0, stream>>>(DEP, bars, XH, Wh, Wv, vals0, WSb, ISb, NV, RETR, HB, HH);
  kLogits<<<dim3(250, 16), 256, 0, stream>>>(HH, WoutT, bout, Cout);
}

// Round 5
// 481.874 us; speedup vs baseline: 1.3254x; 1.3254x over previous
//
#include <hip/hip_runtime.h>

typedef _Float16 half_t;
typedef _Float16 half8 __attribute__((ext_vector_type(8)));
typedef float f32x4 __attribute__((ext_vector_type(4)));

// dims: T=64 B=32 V=32000 E=512 H=512 N=512 DK=256 DV=512, TB=2048

__device__ __forceinline__ void gload_lds16(const void* g, void* l) {
  __builtin_amdgcn_global_load_lds((const __attribute__((address_space(1))) void*)g,
                                   (__attribute__((address_space(3))) void*)l, 16, 0, 0);
}

// ---------------- Wout [512,32000] f32 -> WoutT [32000,512] f16 ----------------
__global__ __launch_bounds__(256) void kConvT(const float* __restrict__ Wout,
                                              half_t* __restrict__ WoutT) {
  __shared__ half_t tile[64][68];
  int n0 = blockIdx.x * 64, k0 = blockIdx.y * 64;
  for (int p = 0; p < 4; p++) {
    int id = p * 256 + threadIdx.x;
    int k = id >> 4, nq = id & 15;
    float4 v = *(const float4*)&Wout[(size_t)(k0 + k) * 32000 + n0 + nq * 4];
    tile[nq * 4 + 0][k] = (half_t)v.x; tile[nq * 4 + 1][k] = (half_t)v.y;
    tile[nq * 4 + 2][k] = (half_t)v.z; tile[nq * 4 + 3][k] = (half_t)v.w;
  }
  __syncthreads();
  for (int p = 0; p < 2; p++) {
    int id = p * 256 + threadIdx.x;
    int n = id >> 3, kc = id & 7;
    half8 h = *(const half8*)&tile[n][kc * 8];
    *(half8*)&WoutT[(size_t)(n0 + n) * 512 + k0 + kc * 8] = h;
  }
}

// ---------------- Wh [1024,512] f32 -> W1T/W2T [512][512] f16 (transposed) ------
__global__ __launch_bounds__(256) void kWhT(const float* __restrict__ Wh,
                                            half_t* __restrict__ W1T,
                                            half_t* __restrict__ W2T) {
  __shared__ half_t tile[64][66];
  int n0 = blockIdx.x * 64, k0 = blockIdx.y * 64;
  for (int p = 0; p < 16; p++) {
    int id = p * 256 + threadIdx.x;
    int kk = id >> 6, nn = id & 63;
    tile[nn][kk] = (half_t)Wh[(size_t)(k0 + kk) * 512 + n0 + nn];
  }
  __syncthreads();
  half_t* out = (k0 < 512) ? W1T : W2T;
  int kb = k0 & 511;
  for (int p = 0; p < 16; p++) {
    int id = p * 256 + threadIdx.x;
    int nn = id >> 6, kk = id & 63;
    out[(size_t)(n0 + nn) * 512 + kb + kk] = tile[nn][kk];
  }
}

// ---------------- X gather + f16 copy + per-t mean (fp64) ----------------
__global__ __launch_bounds__(256) void kGatherXM(const int* __restrict__ tok,
                                                 const float* __restrict__ emb,
                                                 float* __restrict__ X,
                                                 half_t* __restrict__ Xh,
                                                 double* __restrict__ XM) {
  int t = blockIdx.x, c = threadIdx.x;
  double s0 = 0.0, s1 = 0.0;
  for (int b = 0; b < 32; b++) {
    int row = t * 32 + b;
    const float* src = emb + (size_t)tok[row] * 512;
    float v0 = src[c], v1 = src[c + 256];
    X[(size_t)row * 512 + c] = v0; X[(size_t)row * 512 + c + 256] = v1;
    Xh[(size_t)row * 512 + c] = (half_t)v0; Xh[(size_t)row * 512 + c + 256] = (half_t)v1;
    s0 += (double)v0; s1 += (double)v1;
  }
  XM[(size_t)t * 512 + c] = s0 * (1.0 / 32.0);
  XM[(size_t)t * 512 + c + 256] = s1 * (1.0 / 32.0);
}

// ---------------- Q = X @ Wq (double accum) + fp32 copy, 4 rows per WG ---------
__global__ __launch_bounds__(256) void kQ(const float* __restrict__ X,
                                          const float* __restrict__ Wq,
                                          double* __restrict__ Q,
                                          float* __restrict__ Q32) {
  __shared__ float xs[4][512];
  int r0 = blockIdx.x * 4;
  for (int p = 0; p < 8; p++) {
    int id = p * 256 + threadIdx.x;
    int r = id >> 9, i = id & 511;
    xs[r][i] = X[(size_t)(r0 + r) * 512 + i];
  }
  __syncthreads();
  int d = threadIdx.x;
  double a0 = 0, a1 = 0, a2 = 0, a3 = 0;
  #pragma unroll 4
  for (int i = 0; i < 512; i++) {
    double w = (double)Wq[(size_t)i * 256 + d];
    a0 += (double)xs[0][i] * w; a1 += (double)xs[1][i] * w;
    a2 += (double)xs[2][i] * w; a3 += (double)xs[3][i] * w;
  }
  Q[(size_t)(r0 + 0) * 256 + d] = a0; Q[(size_t)(r0 + 1) * 256 + d] = a1;
  Q[(size_t)(r0 + 2) * 256 + d] = a2; Q[(size_t)(r0 + 3) * 256 + d] = a3;
  Q32[(size_t)(r0 + 0) * 256 + d] = (float)a0; Q32[(size_t)(r0 + 1) * 256 + d] = (float)a1;
  Q32[(size_t)(r0 + 2) * 256 + d] = (float)a2; Q32[(size_t)(r0 + 3) * 256 + d] = (float)a3;
}

// ---------------- NK = Xmean @ Wk (double) ----------------
__global__ __launch_bounds__(256) void kNK(const double* __restrict__ XM,
                                           const float* __restrict__ Wk,
                                           double* __restrict__ NK) {
  __shared__ double xm[512];
  int t = blockIdx.x;
  for (int i = threadIdx.x; i < 512; i += 256) xm[i] = XM[(size_t)t * 512 + i];
  __syncthreads();
  int d = threadIdx.x;
  double a = 0;
  #pragma unroll 4
  for (int i = 0; i < 512; i++) a += xm[i] * (double)Wk[(size_t)i * 256 + d];
  NK[(size_t)t * 256 + d] = a;
}

// ---------------- KC[576][256] f32 = concat(keys0, NK32) ----------------
__global__ __launch_bounds__(256) void kKC(const float* __restrict__ keys0,
                                           const double* __restrict__ NKd,
                                           float* __restrict__ KC) {
  int row = blockIdx.x, c = threadIdx.x;
  KC[(size_t)row * 256 + c] = (row < 512) ? keys0[(size_t)row * 256 + c]
                                          : (float)NKd[(size_t)(row - 512) * 256 + c];
}

// ---------------- S[2048][576] = Q32 @ KC^T (fp32 tiled GEMM) ----------------
__global__ __launch_bounds__(256) void kS(const float* __restrict__ Q32,
                                          const float* __restrict__ KC,
                                          float* __restrict__ S) {
  __shared__ float As[32][68];
  __shared__ float Bs[32][68];
  int m0 = blockIdx.x * 64, n0 = blockIdx.y * 64;
  int tid = threadIdx.x;
  int tx = tid & 15, ty = tid >> 4;
  float acc[4][4];
  #pragma unroll
  for (int i = 0; i < 4; i++)
    #pragma unroll
    for (int j = 0; j < 4; j++) acc[i][j] = 0.f;
  for (int kc = 0; kc < 256; kc += 32) {
    __syncthreads();
    #pragma unroll
    for (int p = 0; p < 8; p++) {
      int idx = p * 256 + tid;
      int k = idx & 31, m = idx >> 5;
      As[k][m] = Q32[(size_t)(m0 + m) * 256 + kc + k];
      Bs[k][m] = KC[(size_t)(n0 + m) * 256 + kc + k];
    }
    __syncthreads();
    #pragma unroll
    for (int k = 0; k < 32; k++) {
      float4 a = *(const float4*)&As[k][ty * 4];
      float4 b = *(const float4*)&Bs[k][tx * 4];
      acc[0][0] += a.x * b.x; acc[0][1] += a.x * b.y; acc[0][2] += a.x * b.z; acc[0][3] += a.x * b.w;
      acc[1][0] += a.y * b.x; acc[1][1] += a.y * b.y; acc[1][2] += a.y * b.z; acc[1][3] += a.y * b.w;
      acc[2][0] += a.z * b.x; acc[2][1] += a.z * b.y; acc[2][2] += a.z * b.z; acc[2][3] += a.z * b.w;
      acc[3][0] += a.w * b.x; acc[3][1] += a.w * b.y; acc[3][2] += a.w * b.z; acc[3][3] += a.w * b.w;
    }
  }
  #pragma unroll
  for (int i = 0; i < 4; i++) {
    float4 o = {acc[i][0], acc[i][1], acc[i][2], acc[i][3]};
    *(float4*)&S[(size_t)(m0 + ty * 4 + i) * 576 + n0 + tx * 4] = o;
  }
}

// ---------------- per-row: fp32 top-16 -> fp64 rescore -> top-8 + softmax ------
__global__ __launch_bounds__(256) void kTopk(const float* __restrict__ S,
                                             const double* __restrict__ Qd,
                                             const double* __restrict__ NKd,
                                             const float* __restrict__ keys0,
                                             float* __restrict__ WSo,
                                             int* __restrict__ ISo) {
  int row = blockIdx.x * 4 + (threadIdx.x >> 6);
  int lane = threadIdx.x & 63;
  int t = row >> 5;
  const float* Srow = S + (size_t)row * 576;
  float v[8];
  #pragma unroll
  for (int j = 0; j < 8; j++) v[j] = Srow[j * 64 + lane];
  if (lane < t) v[0] = Srow[512 + lane];
  float cv[16]; int ci[16];
  #pragma unroll
  for (int it = 0; it < 16; it++) {
    float bv = -1e30f; int bi = 0x7fffffff;
    #pragma unroll
    for (int j = 0; j < 8; j++) {
      int ii = j * 64 + lane;
      if (v[j] > bv || (v[j] == bv && ii < bi)) { bv = v[j]; bi = ii; }
    }
    #pragma unroll
    for (int s = 32; s > 0; s >>= 1) {
      float ov = __shfl_xor(bv, s, 64);
      int oi = __shfl_xor(bi, s, 64);
      if (ov > bv || (ov == bv && oi < bi)) { bv = ov; bi = oi; }
    }
    cv[it] = bv; ci[it] = bi;
    #pragma unroll
    for (int j = 0; j < 8; j++)
      if (j * 64 + lane == bi) v[j] = -1e30f;
  }
  (void)cv;
  // fp64 rescore of the 16 candidates
  const double* qrow = Qd + (size_t)row * 256 + lane * 4;
  double q0 = qrow[0], q1 = qrow[1], q2 = qrow[2], q3 = qrow[3];
  double dv[16];
  #pragma unroll
  for (int c = 0; c < 16; c++) {
    int idx = ci[c];
    double p;
    if (idx < t) {
      const double* kr = NKd + (size_t)idx * 256 + lane * 4;
      p = q0 * kr[0] + q1 * kr[1] + q2 * kr[2] + q3 * kr[3];
    } else {
      const float* kr = keys0 + (size_t)idx * 256 + lane * 4;
      p = q0 * (double)kr[0] + q1 * (double)kr[1] + q2 * (double)kr[2] + q3 * (double)kr[3];
    }
    #pragma unroll
    for (int s = 32; s > 0; s >>= 1) p += __shfl_xor(p, s, 64);
    dv[c] = p * 0.0625;
  }
  // top-8 of 16 by (value desc, index asc)
  double tv[8]; int ti[8];
  #pragma unroll
  for (int it = 0; it < 8; it++) {
    double bv = -1e300; int bi = 0x7fffffff;
    #pragma unroll
    for (int c = 0; c < 16; c++)
      if (dv[c] > bv || (dv[c] == bv && ci[c] < bi)) { bv = dv[c]; bi = ci[c]; }
    tv[it] = bv; ti[it] = bi;
    #pragma unroll
    for (int c = 0; c < 16; c++)
      if (ci[c] == bi) dv[c] = -1e300;
  }
  if (lane == 0) {
    double m = tv[0], ev[8], Z = 0;
    #pragma unroll
    for (int i2 = 0; i2 < 8; i2++) { ev[i2] = exp(tv[i2] - m); Z += ev[i2]; }
    double inv = 1.0 / Z;
    #pragma unroll
    for (int i2 = 0; i2 < 8; i2++) {
      WSo[(size_t)row * 8 + i2] = (float)(ev[i2] * inv);
      ISo[(size_t)row * 8 + i2] = ti[i2];
    }
  }
}

// ---------------- fast-path retrieved -> fp16; + DEP flags + bars zero ---------
__global__ __launch_bounds__(256) void kRetrDeps(const float* __restrict__ vals0,
                                                 const float* __restrict__ WSo,
                                                 const int* __restrict__ ISo,
                                                 half_t* __restrict__ R16,
                                                 int* __restrict__ DEP,
                                                 int* __restrict__ bars) {
  int bid = blockIdx.x;
  if (bid >= 2048) {  // kDeps role
    int t = bid - 2048;
    __shared__ int f;
    if (threadIdx.x == 0) f = 0;
    __syncthreads();
    int idx = ISo[(size_t)t * 256 + threadIdx.x];
    if (idx < t) atomicOr(&f, 1);
    __syncthreads();
    if (threadIdx.x == 0) DEP[t] = f;
    if (t == 0) bars[threadIdx.x] = 0;
    return;
  }
  __shared__ float wl[8];
  __shared__ int il[8];
  int row = bid;
  if (threadIdx.x < 8) {
    wl[threadIdx.x] = WSo[(size_t)row * 8 + threadIdx.x];
    il[threadIdx.x] = ISo[(size_t)row * 8 + threadIdx.x];
  }
  __syncthreads();
  int c = threadIdx.x;
  float a0 = 0.f, a1 = 0.f;
  #pragma unroll
  for (int k2 = 0; k2 < 8; k2++) {
    const float* src = vals0 + (size_t)il[k2] * 512;
    a0 += wl[k2] * src[c];
    a1 += wl[k2] * src[c + 256];
  }
  R16[(size_t)row * 512 + c] = (half_t)a0;
  R16[(size_t)row * 512 + c + 256] = (half_t)a1;
}

// ------- fused: acc = Xh@W1T^T (write XH+bh) + R16@W2T^T; HH=tanh(acc+bh); HM --
__global__ __launch_bounds__(256) void kFused(const half_t* __restrict__ Xh,
                                              const half_t* __restrict__ R16,
                                              const half_t* __restrict__ W1T,
                                              const half_t* __restrict__ W2T,
                                              const float* __restrict__ bh,
                                              float* __restrict__ XH,
                                              half_t* __restrict__ HH,
                                              float* __restrict__ HM) {
  __shared__ half_t lA[128 * 32];
  __shared__ half_t lB[128 * 32];
  int n0 = blockIdx.x * 128, m0 = blockIdx.y * 128;
  int tid = threadIdx.x, wid = tid >> 6, lane = tid & 63;
  int wm = wid >> 1, wn = wid & 1;
  f32x4 acc[4][4];
  #pragma unroll
  for (int a2 = 0; a2 < 4; a2++)
    #pragma unroll
    for (int b2 = 0; b2 < 4; b2++) acc[a2][b2] = (f32x4){0.f, 0.f, 0.f, 0.f};
  int rA = lane >> 2;
  int cswz = ((lane & 3) ^ ((lane >> 3) & 3)) * 8;
  int koffs = (((lane >> 4) ^ ((lane >> 1) & 3))) * 8;
  for (int kt = 0; kt < 32; kt++) {
    const half_t* Ap = (kt < 16) ? Xh : R16;
    const half_t* Bp = (kt < 16) ? W1T : W2T;
    int kk = kt & 15;
    __syncthreads();
    #pragma unroll
    for (int i2 = 0; i2 < 2; i2++) {
      int blk = wid * 2 + i2;
      gload_lds16(Ap + ((size_t)(m0 + blk * 16 + rA) * 512 + kk * 32 + cswz), (void*)(lA + blk * 512));
      gload_lds16(Bp + ((size_t)(n0 + blk * 16 + rA) * 512 + kk * 32 + cswz), (void*)(lB + blk * 512));
    }
    asm volatile("s_waitcnt vmcnt(0)" ::: "memory");
    __syncthreads();
    half8 af[4], bf[4];
    #pragma unroll
    for (int mf = 0; mf < 4; mf++)
      af[mf] = *(const half8*)&lA[(wm * 64 + mf * 16 + (lane & 15)) * 32 + koffs];
    #pragma unroll
    for (int nf = 0; nf < 4; nf++)
      bf[nf] = *(const half8*)&lB[(wn * 64 + nf * 16 + (lane & 15)) * 32 + koffs];
    #pragma unroll
    for (int mf = 0; mf < 4; mf++)
      #pragma unroll
      for (int nf = 0; nf < 4; nf++)
        acc[mf][nf] = __builtin_amdgcn_mfma_f32_16x16x32_f16(af[mf], bf[nf], acc[mf][nf], 0, 0, 0);
    if (kt == 15) {
      #pragma unroll
      for (int nf = 0; nf < 4; nf++) {
        int col = n0 + wn * 64 + nf * 16 + (lane & 15);
        float bv = bh[col];
        #pragma unroll
        for (int mf = 0; mf < 4; mf++) {
          int rbase = m0 + wm * 64 + mf * 16 + (lane >> 4) * 4;
          #pragma unroll
          for (int r = 0; r < 4; r++)
            XH[(size_t)(rbase + r) * 512 + col] = acc[mf][nf][r] + bv;
        }
      }
    }
  }
  #pragma unroll
  for (int tt = 0; tt < 2; tt++) {
    #pragma unroll
    for (int nf = 0; nf < 4; nf++) {
      int col = n0 + wn * 64 + nf * 16 + (lane & 15);
      float bv = bh[col];
      float cs = 0.f;
      #pragma unroll
      for (int mfp = 0; mfp < 2; mfp++) {
        int mf = tt * 2 + mfp;
        int rbase = m0 + wm * 64 + mf * 16 + (lane >> 4) * 4;
        #pragma unroll
        for (int r = 0; r < 4; r++) {
          float v = tanhf(acc[mf][nf][r] + bv);
          HH[(size_t)(rbase + r) * 512 + col] = (half_t)v;
          cs += v;
        }
      }
      cs += __shfl_xor(cs, 16, 64);
      cs += __shfl_xor(cs, 32, 64);
      if ((lane >> 4) == 0) {
        int t = (m0 >> 5) + wm * 2 + tt;
        HM[(size_t)t * 512 + col] = cs * (1.f / 32.f);
      }
    }
  }
}

// ---------------- NV[t] = hmean[t] @ Wv ----------------
__global__ __launch_bounds__(256) void kNVall(const float* __restrict__ HMm,
                                              const float* __restrict__ Wv,
                                              float* __restrict__ NV) {
  __shared__ float hm[512];
  int t = blockIdx.x;
  hm[threadIdx.x] = HMm[(size_t)t * 512 + threadIdx.x];
  hm[threadIdx.x + 256] = HMm[(size_t)t * 512 + threadIdx.x + 256];
  __syncthreads();
  for (int v = threadIdx.x; v < 512; v += 256) {
    float a = 0.f;
    #pragma unroll 4
    for (int i = 0; i < 512; i++) a += hm[i] * Wv[(size_t)i * 512 + v];
    NV[(size_t)t * 512 + v] = a;
  }
}

// ---------------- grid barrier (64 resident WGs) ----------------
__device__ __forceinline__ void gbar(int* bars, int id, int nwg) {
  __syncthreads();
  if (threadIdx.x == 0) {
    __hip_atomic_fetch_add(&bars[id], 1, __ATOMIC_ACQ_REL, __HIP_MEMORY_SCOPE_AGENT);
    while (__hip_atomic_load(&bars[id], __ATOMIC_ACQUIRE, __HIP_MEMORY_SCOPE_AGENT) < nwg)
      __builtin_amdgcn_s_sleep(4);
  }
  __syncthreads();
}

// ---------------- sequential fixup for steps that selected generated slots -----
__global__ __launch_bounds__(256) void kFixup(const int* __restrict__ DEP,
                                              int* __restrict__ bars,
                                              const float* __restrict__ XHm,
                                              const float* __restrict__ Wh,
                                              const float* __restrict__ Wv,
                                              const float* __restrict__ vals0,
                                              const float* __restrict__ WSo,
                                              const int* __restrict__ ISo,
                                              float* __restrict__ NV,
                                              float* __restrict__ RETR,
                                              float* __restrict__ HB,
                                              half_t* __restrict__ HHm) {
  __shared__ float rl[512];
  __shared__ float hm2[512];
  int w = blockIdx.x;
  int barid = 0;
  for (int t = 0; t < 64; t++) {
    if (DEP[t] == 0) continue;
    {
      int b = w >> 1, hf = w & 1;
      int c = hf * 256 + threadIdx.x;
      int row = t * 32 + b;
      float acc = 0.f;
      #pragma unroll
      for (int k2 = 0; k2 < 8; k2++) {
        int idx = ISo[(size_t)row * 8 + k2];
        float wv2 = WSo[(size_t)row * 8 + k2];
        const float* src = (idx < t) ? (NV + (size_t)idx * 512) : (vals0 + (size_t)idx * 512);
        acc += wv2 * src[c];
      }
      RETR[(size_t)b * 512 + c] = acc;
    }
    gbar(bars, barid++, 64);
    if (w < 32) {
      int b = w;
      rl[threadIdx.x] = RETR[(size_t)b * 512 + threadIdx.x];
      rl[threadIdx.x + 256] = RETR[(size_t)b * 512 + threadIdx.x + 256];
      __syncthreads();
      int row = t * 32 + b;
      for (int cc = 0; cc < 2; cc++) {
        int col = cc * 256 + threadIdx.x;
        float acc = 0.f;
        #pragma unroll 4
        for (int i = 0; i < 512; i++) acc += rl[i] * Wh[(size_t)(512 + i) * 512 + col];
        float h = tanhf(XHm[(size_t)row * 512 + col] + acc);
        HB[(size_t)b * 512 + col] = h;
        HHm[(size_t)row * 512 + col] = (half_t)h;
      }
    }
    gbar(bars, barid++, 64);
    if (w == 0) {
      for (int j = threadIdx.x; j < 512; j += 256) {
        float s = 0.f;
        for (int b = 0; b < 32; b++) s += HB[(size_t)b * 512 + j];
        hm2[j] = s * (1.f / 32.f);
      }
      __syncthreads();
      for (int v = threadIdx.x; v < 512; v += 256) {
        float a = 0.f;
        #pragma unroll 4
        for (int i = 0; i < 512; i++) a += hm2[i] * Wv[(size_t)i * 512 + v];
        NV[(size_t)t * 512 + v] = a;
      }
    }
    gbar(bars, barid++, 64);
  }
}

// ---------------- logits = HH @ WoutT^T + bout  (fp16 MFMA, swizzled LDS) ------
__global__ __launch_bounds__(256) void kLogits(const half_t* __restrict__ A,
                                               const half_t* __restrict__ Bm,
                                               const float* __restrict__ bout,
                                               float* __restrict__ C) {
  __shared__ half_t lA[128 * 32];
  __shared__ half_t lB[128 * 32];
  int lin = blockIdx.y * 250 + blockIdx.x;
  int swz = (lin & 7) * 500 + (lin >> 3);
  int m0 = (swz & 15) * 128;
  int n0 = (swz >> 4) * 128;
  int tid = threadIdx.x, wid = tid >> 6, lane = tid & 63;
  int wm = wid >> 1, wn = wid & 1;
  f32x4 acc[4][4];
  #pragma unroll
  for (int a2 = 0; a2 < 4; a2++)
    #pragma unroll
    for (int b2 = 0; b2 < 4; b2++) acc[a2][b2] = (f32x4){0.f, 0.f, 0.f, 0.f};

  int rA = lane >> 2;
  int cswz = ((lane & 3) ^ ((lane >> 3) & 3)) * 8;
  int koffs = (((lane >> 4) ^ ((lane >> 1) & 3))) * 8;
  for (int kt = 0; kt < 16; kt++) {
    __syncthreads();
    #pragma unroll
    for (int i2 = 0; i2 < 2; i2++) {
      int blk = wid * 2 + i2;
      gload_lds16(A + ((size_t)(m0 + blk * 16 + rA) * 512 + kt * 32 + cswz), (void*)(lA + blk * 512));
      gload_lds16(Bm + ((size_t)(n0 + blk * 16 + rA) * 512 + kt * 32 + cswz), (void*)(lB + blk * 512));
    }
    asm volatile("s_waitcnt vmcnt(0)" ::: "memory");
    __syncthreads();
    half8 af[4], bf[4];
    #pragma unroll
    for (int mf = 0; mf < 4; mf++)
      af[mf] = *(const half8*)&lA[(wm * 64 + mf * 16 + (lane & 15)) * 32 + koffs];
    #pragma unroll
    for (int nf = 0; nf < 4; nf++)
      bf[nf] = *(const half8*)&lB[(wn * 64 + nf * 16 + (lane & 15)) * 32 + koffs];
    #pragma unroll
    for (int mf = 0; mf < 4; mf++)
      #pragma unroll
      for (int nf = 0; nf < 4; nf++)
        acc[mf][nf] = __builtin_amdgcn_mfma_f32_16x16x32_f16(af[mf], bf[nf], acc[mf][nf], 0, 0, 0);
  }
  #pragma unroll
  for (int nf = 0; nf < 4; nf++) {
    int col = n0 + wn * 64 + nf * 16 + (lane & 15);
    float bv = bout[col];
    #pragma unroll
    for (int mf = 0; mf < 4; mf++) {
      int rbase = m0 + wm * 64 + mf * 16 + (lane >> 4) * 4;
      #pragma unroll
      for (int r = 0; r < 4; r++)
        C[(size_t)(rbase + r) * 32000 + col] = acc[mf][nf][r] + bv;
    }
  }
}

extern "C" void kernel_launch(void* const* d_in, const int* in_sizes, int n_in,
                              void* d_out, int out_size, void* d_ws, size_t ws_size,
                              hipStream_t stream) {
  (void)in_sizes; (void)n_in; (void)out_size; (void)ws_size;
  const int*   tok   = (const int*)d_in[0];
  const float* emb   = (const float*)d_in[1];
  const float* Wq    = (const float*)d_in[2];
  const float* Wk    = (const float*)d_in[3];
  const float* Wv    = (const float*)d_in[4];
  const float* Wh    = (const float*)d_in[5];
  const float* bh    = (const float*)d_in[6];
  const float* Wout  = (const float*)d_in[7];
  const float* bout  = (const float*)d_in[8];
  const float* keys0 = (const float*)d_in[9];
  const float* vals0 = (const float*)d_in[10];
  float* Cout = (float*)d_out;

  char* ws = (char*)d_ws;
  size_t off = 0;
  auto alloc = [&](size_t bytes) -> char* {
    char* p = ws + off;
    off += (bytes + 255) & ~(size_t)255;
    return p;
  };
  half_t* WoutT = (half_t*)alloc(32768000);  // [32000][512] f16
  half_t* W1T   = (half_t*)alloc(524288);    // [512][512] f16
  half_t* W2T   = (half_t*)alloc(524288);    // [512][512] f16
  float*  X     = (float*) alloc(4194304);   // [2048][512]
  half_t* Xh    = (half_t*)alloc(2097152);   // [2048][512] f16
  double* Qd    = (double*)alloc(4194304);   // [2048][256]
  float*  Q32   = (float*) alloc(2097152);   // [2048][256] f32
  double* NKd   = (double*)alloc(131072);    // [64][256]
  double* XM    = (double*)alloc(262144);    // [64][512]
  float*  KC    = (float*) alloc(589824);    // [576][256] f32
  float*  Sb    = (float*) alloc(4718592);   // [2048][576] f32
  float*  XH    = (float*) alloc(4194304);   // [2048][512]
  float*  WSb   = (float*) alloc(65536);     // [2048][8]
  int*    ISb   = (int*)   alloc(65536);     // [2048][8]
  float*  NV    = (float*) alloc(131072);    // [64][512]
  half_t* R16   = (half_t*)alloc(2097152);   // [2048][512] f16
  half_t* HH    = (half_t*)alloc(2097152);   // [2048][512]
  float*  HM    = (float*) alloc(131072);    // [64][512]
  float*  RETR  = (float*) alloc(65536);     // [32][512]
  float*  HB    = (float*) alloc(65536);     // [32][512]
  int*    DEP   = (int*)   alloc(256);       // [64]
  int*    bars  = (int*)   alloc(1024);      // [256]

  kConvT<<<dim3(500, 8), 256, 0, stream>>>(Wout, WoutT);
  kWhT<<<dim3(8, 16), 256, 0, stream>>>(Wh, W1T, W2T);
  kGatherXM<<<64, 256, 0, stream>>>(tok, emb, X, Xh, XM);
  kQ<<<512, 256, 0, stream>>>(X, Wq, Qd, Q32);
  kNK<<<64, 256, 0, stream>>>(XM, Wk, NKd);
  kKC<<<576, 256, 0, stream>>>(keys0, NKd, KC);
  kS<<<dim3(32, 9), 256, 0, stream>>>(Q32, KC, Sb);
  kTopk<<<512, 256, 0, stream>>>(Sb, Qd, NKd, keys0, WSb, ISb);
  kRetrDeps<<<2112, 256, 0, stream>>>(vals0, WSb, ISb, R16, DEP, bars);
  kFused<<<dim3(4, 16), 256, 0, stream>>>(Xh, R16, W1T, W2T, bh, XH, HH, HM);
  kNVall<<<64, 256, 0, stream>>>(HM, Wv, NV);
  kFixup<<<64, 256, 0, stream>>>(DEP, bars, XH, Wh, Wv, vals0, WSb, ISb, NV, RETR, HB, HH);
  kLogits<<<dim3(250, 16), 256, 0, stream>>>(HH, WoutT, bout, Cout);
}

// Round 6
// 479.604 us; speedup vs baseline: 1.3317x; 1.0047x over previous
//
#include <hip/hip_runtime.h>

typedef _Float16 half_t;
typedef _Float16 half8 __attribute__((ext_vector_type(8)));
typedef float f32x4 __attribute__((ext_vector_type(4)));

// dims: T=64 B=32 V=32000 E=512 H=512 N=512 DK=256 DV=512, TB=2048

__device__ __forceinline__ void gload_lds16(const void* g, void* l) {
  __builtin_amdgcn_global_load_lds((const __attribute__((address_space(1))) void*)g,
                                   (__attribute__((address_space(3))) void*)l, 16, 0, 0);
}

// ------- kPrep: blocks 0..3999: Wout^T -> f16; blocks 4000..4127: Wh^T -> W1T/W2T
__global__ __launch_bounds__(256) void kPrep(const float* __restrict__ Wout,
                                             half_t* __restrict__ WoutT,
                                             const float* __restrict__ Wh,
                                             half_t* __restrict__ W1T,
                                             half_t* __restrict__ W2T) {
  __shared__ half_t tile[64][68];
  int bid = blockIdx.x;
  if (bid < 4000) {
    int n0 = (bid % 500) * 64, k0 = (bid / 500) * 64;
    for (int p = 0; p < 4; p++) {
      int id = p * 256 + threadIdx.x;
      int k = id >> 4, nq = id & 15;
      float4 v = *(const float4*)&Wout[(size_t)(k0 + k) * 32000 + n0 + nq * 4];
      tile[nq * 4 + 0][k] = (half_t)v.x; tile[nq * 4 + 1][k] = (half_t)v.y;
      tile[nq * 4 + 2][k] = (half_t)v.z; tile[nq * 4 + 3][k] = (half_t)v.w;
    }
    __syncthreads();
    for (int p = 0; p < 2; p++) {
      int id = p * 256 + threadIdx.x;
      int n = id >> 3, kc = id & 7;
      half8 h = *(const half8*)&tile[n][kc * 8];
      *(half8*)&WoutT[(size_t)(n0 + n) * 512 + k0 + kc * 8] = h;
    }
  } else {
    int id2 = bid - 4000;
    int n0 = (id2 & 7) * 64, k0 = (id2 >> 3) * 64;
    for (int p = 0; p < 16; p++) {
      int id = p * 256 + threadIdx.x;
      int kk = id >> 6, nn = id & 63;
      tile[nn][kk] = (half_t)Wh[(size_t)(k0 + kk) * 512 + n0 + nn];
    }
    __syncthreads();
    half_t* out = (k0 < 512) ? W1T : W2T;
    int kb = k0 & 511;
    for (int p = 0; p < 16; p++) {
      int id = p * 256 + threadIdx.x;
      int nn = id >> 6, kk = id & 63;
      out[(size_t)(n0 + nn) * 512 + kb + kk] = tile[nn][kk];
    }
  }
}

// ------- X gather + f16 copy + per-t mean (fp64); blocks >=64 copy keys0 -> KC -
__global__ __launch_bounds__(256) void kGatherXM(const int* __restrict__ tok,
                                                 const float* __restrict__ emb,
                                                 float* __restrict__ X,
                                                 half_t* __restrict__ Xh,
                                                 double* __restrict__ XM,
                                                 const float* __restrict__ keys0,
                                                 float* __restrict__ KC) {
  if (blockIdx.x >= 64) {
    int row = blockIdx.x - 64;
    KC[(size_t)row * 256 + threadIdx.x] = keys0[(size_t)row * 256 + threadIdx.x];
    return;
  }
  int t = blockIdx.x, c = threadIdx.x;
  double s0 = 0.0, s1 = 0.0;
  for (int b = 0; b < 32; b++) {
    int row = t * 32 + b;
    const float* src = emb + (size_t)tok[row] * 512;
    float v0 = src[c], v1 = src[c + 256];
    X[(size_t)row * 512 + c] = v0; X[(size_t)row * 512 + c + 256] = v1;
    Xh[(size_t)row * 512 + c] = (half_t)v0; Xh[(size_t)row * 512 + c + 256] = (half_t)v1;
    s0 += (double)v0; s1 += (double)v1;
  }
  XM[(size_t)t * 512 + c] = s0 * (1.0 / 32.0);
  XM[(size_t)t * 512 + c + 256] = s1 * (1.0 / 32.0);
}

// ---------------- Q = X @ Wq (double accum) + fp32 copy, 4 rows per WG ---------
__global__ __launch_bounds__(256) void kQ(const float* __restrict__ X,
                                          const float* __restrict__ Wq,
                                          double* __restrict__ Q,
                                          float* __restrict__ Q32) {
  __shared__ float xs[4][512];
  int r0 = blockIdx.x * 4;
  for (int p = 0; p < 8; p++) {
    int id = p * 256 + threadIdx.x;
    int r = id >> 9, i = id & 511;
    xs[r][i] = X[(size_t)(r0 + r) * 512 + i];
  }
  __syncthreads();
  int d = threadIdx.x;
  double a0 = 0, a1 = 0, a2 = 0, a3 = 0;
  #pragma unroll 4
  for (int i = 0; i < 512; i++) {
    double w = (double)Wq[(size_t)i * 256 + d];
    a0 += (double)xs[0][i] * w; a1 += (double)xs[1][i] * w;
    a2 += (double)xs[2][i] * w; a3 += (double)xs[3][i] * w;
  }
  Q[(size_t)(r0 + 0) * 256 + d] = a0; Q[(size_t)(r0 + 1) * 256 + d] = a1;
  Q[(size_t)(r0 + 2) * 256 + d] = a2; Q[(size_t)(r0 + 3) * 256 + d] = a3;
  Q32[(size_t)(r0 + 0) * 256 + d] = (float)a0; Q32[(size_t)(r0 + 1) * 256 + d] = (float)a1;
  Q32[(size_t)(r0 + 2) * 256 + d] = (float)a2; Q32[(size_t)(r0 + 3) * 256 + d] = (float)a3;
}

// ---------------- NK = Xmean @ Wk (double); also KC[512+t] f32 ----------------
__global__ __launch_bounds__(256) void kNK(const double* __restrict__ XM,
                                           const float* __restrict__ Wk,
                                           double* __restrict__ NK,
                                           float* __restrict__ KC) {
  __shared__ double xm[512];
  int t = blockIdx.x;
  for (int i = threadIdx.x; i < 512; i += 256) xm[i] = XM[(size_t)t * 512 + i];
  __syncthreads();
  int d = threadIdx.x;
  double a = 0;
  #pragma unroll 4
  for (int i = 0; i < 512; i++) a += xm[i] * (double)Wk[(size_t)i * 256 + d];
  NK[(size_t)t * 256 + d] = a;
  KC[(size_t)(512 + t) * 256 + d] = (float)a;
}

// ---------------- S[2048][576] = Q32 @ KC^T (fp32 tiled GEMM) ----------------
__global__ __launch_bounds__(256) void kS(const float* __restrict__ Q32,
                                          const float* __restrict__ KC,
                                          float* __restrict__ S) {
  __shared__ float As[32][68];
  __shared__ float Bs[32][68];
  int m0 = blockIdx.x * 64, n0 = blockIdx.y * 64;
  int tid = threadIdx.x;
  int tx = tid & 15, ty = tid >> 4;
  float acc[4][4];
  #pragma unroll
  for (int i = 0; i < 4; i++)
    #pragma unroll
    for (int j = 0; j < 4; j++) acc[i][j] = 0.f;
  for (int kc = 0; kc < 256; kc += 32) {
    __syncthreads();
    #pragma unroll
    for (int p = 0; p < 8; p++) {
      int idx = p * 256 + tid;
      int k = idx & 31, m = idx >> 5;
      As[k][m] = Q32[(size_t)(m0 + m) * 256 + kc + k];
      Bs[k][m] = KC[(size_t)(n0 + m) * 256 + kc + k];
    }
    __syncthreads();
    #pragma unroll
    for (int k = 0; k < 32; k++) {
      float4 a = *(const float4*)&As[k][ty * 4];
      float4 b = *(const float4*)&Bs[k][tx * 4];
      acc[0][0] += a.x * b.x; acc[0][1] += a.x * b.y; acc[0][2] += a.x * b.z; acc[0][3] += a.x * b.w;
      acc[1][0] += a.y * b.x; acc[1][1] += a.y * b.y; acc[1][2] += a.y * b.z; acc[1][3] += a.y * b.w;
      acc[2][0] += a.z * b.x; acc[2][1] += a.z * b.y; acc[2][2] += a.z * b.z; acc[2][3] += a.z * b.w;
      acc[3][0] += a.w * b.x; acc[3][1] += a.w * b.y; acc[3][2] += a.w * b.z; acc[3][3] += a.w * b.w;
    }
  }
  #pragma unroll
  for (int i = 0; i < 4; i++) {
    float4 o = {acc[i][0], acc[i][1], acc[i][2], acc[i][3]};
    *(float4*)&S[(size_t)(m0 + ty * 4 + i) * 576 + n0 + tx * 4] = o;
  }
}

// ---------------- per-row: fp32 top-16 -> fp64 rescore -> top-8 + softmax ------
__global__ __launch_bounds__(256) void kTopk(const float* __restrict__ S,
                                             const double* __restrict__ Qd,
                                             const double* __restrict__ NKd,
                                             const float* __restrict__ keys0,
                                             float* __restrict__ WSo,
                                             int* __restrict__ ISo) {
  int row = blockIdx.x * 4 + (threadIdx.x >> 6);
  int lane = threadIdx.x & 63;
  int t = row >> 5;
  const float* Srow = S + (size_t)row * 576;
  float v[8];
  #pragma unroll
  for (int j = 0; j < 8; j++) v[j] = Srow[j * 64 + lane];
  if (lane < t) v[0] = Srow[512 + lane];
  float cv[16]; int ci[16];
  #pragma unroll
  for (int it = 0; it < 16; it++) {
    float bv = -1e30f; int bi = 0x7fffffff;
    #pragma unroll
    for (int j = 0; j < 8; j++) {
      int ii = j * 64 + lane;
      if (v[j] > bv || (v[j] == bv && ii < bi)) { bv = v[j]; bi = ii; }
    }
    #pragma unroll
    for (int s = 32; s > 0; s >>= 1) {
      float ov = __shfl_xor(bv, s, 64);
      int oi = __shfl_xor(bi, s, 64);
      if (ov > bv || (ov == bv && oi < bi)) { bv = ov; bi = oi; }
    }
    cv[it] = bv; ci[it] = bi;
    #pragma unroll
    for (int j = 0; j < 8; j++)
      if (j * 64 + lane == bi) v[j] = -1e30f;
  }
  (void)cv;
  const double* qrow = Qd + (size_t)row * 256 + lane * 4;
  double q0 = qrow[0], q1 = qrow[1], q2 = qrow[2], q3 = qrow[3];
  double dv[16];
  #pragma unroll
  for (int c = 0; c < 16; c++) {
    int idx = ci[c];
    double p;
    if (idx < t) {
      const double* kr = NKd + (size_t)idx * 256 + lane * 4;
      p = q0 * kr[0] + q1 * kr[1] + q2 * kr[2] + q3 * kr[3];
    } else {
      const float* kr = keys0 + (size_t)idx * 256 + lane * 4;
      p = q0 * (double)kr[0] + q1 * (double)kr[1] + q2 * (double)kr[2] + q3 * (double)kr[3];
    }
    #pragma unroll
    for (int s = 32; s > 0; s >>= 1) p += __shfl_xor(p, s, 64);
    dv[c] = p * 0.0625;
  }
  double tv[8]; int ti[8];
  #pragma unroll
  for (int it = 0; it < 8; it++) {
    double bv = -1e300; int bi = 0x7fffffff;
    #pragma unroll
    for (int c = 0; c < 16; c++)
      if (dv[c] > bv || (dv[c] == bv && ci[c] < bi)) { bv = dv[c]; bi = ci[c]; }
    tv[it] = bv; ti[it] = bi;
    #pragma unroll
    for (int c = 0; c < 16; c++)
      if (ci[c] == bi) dv[c] = -1e300;
  }
  if (lane == 0) {
    double m = tv[0], ev[8], Z = 0;
    #pragma unroll
    for (int i2 = 0; i2 < 8; i2++) { ev[i2] = exp(tv[i2] - m); Z += ev[i2]; }
    double inv = 1.0 / Z;
    #pragma unroll
    for (int i2 = 0; i2 < 8; i2++) {
      WSo[(size_t)row * 8 + i2] = (float)(ev[i2] * inv);
      ISo[(size_t)row * 8 + i2] = ti[i2];
    }
  }
}

// ---------------- fast-path retrieved -> fp16; + DEP flags + bars zero ---------
__global__ __launch_bounds__(256) void kRetrDeps(const float* __restrict__ vals0,
                                                 const float* __restrict__ WSo,
                                                 const int* __restrict__ ISo,
                                                 half_t* __restrict__ R16,
                                                 int* __restrict__ DEP,
                                                 int* __restrict__ bars) {
  int bid = blockIdx.x;
  if (bid >= 2048) {
    int t = bid - 2048;
    __shared__ int f;
    if (threadIdx.x == 0) f = 0;
    __syncthreads();
    int idx = ISo[(size_t)t * 256 + threadIdx.x];
    if (idx < t) atomicOr(&f, 1);
    __syncthreads();
    if (threadIdx.x == 0) DEP[t] = f;
    if (t == 0) bars[threadIdx.x] = 0;
    return;
  }
  __shared__ float wl[8];
  __shared__ int il[8];
  int row = bid;
  if (threadIdx.x < 8) {
    wl[threadIdx.x] = WSo[(size_t)row * 8 + threadIdx.x];
    il[threadIdx.x] = ISo[(size_t)row * 8 + threadIdx.x];
  }
  __syncthreads();
  int c = threadIdx.x;
  float a0 = 0.f, a1 = 0.f;
  #pragma unroll
  for (int k2 = 0; k2 < 8; k2++) {
    const float* src = vals0 + (size_t)il[k2] * 512;
    a0 += wl[k2] * src[c];
    a1 += wl[k2] * src[c + 256];
  }
  R16[(size_t)row * 512 + c] = (half_t)a0;
  R16[(size_t)row * 512 + c + 256] = (half_t)a1;
}

// ------- fused concat-GEMM (2-phase prefetch): XH write at K-mid; HH=tanh; HM --
__global__ __launch_bounds__(256) void kFused(const half_t* __restrict__ Xh,
                                              const half_t* __restrict__ R16,
                                              const half_t* __restrict__ W1T,
                                              const half_t* __restrict__ W2T,
                                              const float* __restrict__ bh,
                                              float* __restrict__ XH,
                                              half_t* __restrict__ HH,
                                              float* __restrict__ HM) {
  __shared__ half_t lA[2][128 * 32];
  __shared__ half_t lB[2][128 * 32];
  int n0 = blockIdx.x * 128, m0 = blockIdx.y * 128;
  int tid = threadIdx.x, wid = tid >> 6, lane = tid & 63;
  int wm = wid >> 1, wn = wid & 1;
  f32x4 acc[4][4];
  #pragma unroll
  for (int a2 = 0; a2 < 4; a2++)
    #pragma unroll
    for (int b2 = 0; b2 < 4; b2++) acc[a2][b2] = (f32x4){0.f, 0.f, 0.f, 0.f};
  int rA = lane >> 2;
  int cswz = ((lane & 3) ^ ((lane >> 3) & 3)) * 8;
  int koffs = (((lane >> 4) ^ ((lane >> 1) & 3))) * 8;
  // prologue: stage kt=0 into buf 0
  #pragma unroll
  for (int i2 = 0; i2 < 2; i2++) {
    int blk = wid * 2 + i2;
    gload_lds16(Xh + ((size_t)(m0 + blk * 16 + rA) * 512 + cswz), (void*)(&lA[0][blk * 512]));
    gload_lds16(W1T + ((size_t)(n0 + blk * 16 + rA) * 512 + cswz), (void*)(&lB[0][blk * 512]));
  }
  asm volatile("s_waitcnt vmcnt(0)" ::: "memory");
  __syncthreads();
  int cur = 0;
  for (int kt = 0; kt < 32; kt++) {
    if (kt < 31) {
      int j = kt + 1;
      const half_t* Ap = (j < 16) ? Xh : R16;
      const half_t* Bp = (j < 16) ? W1T : W2T;
      int kk = j & 15;
      #pragma unroll
      for (int i2 = 0; i2 < 2; i2++) {
        int blk = wid * 2 + i2;
        gload_lds16(Ap + ((size_t)(m0 + blk * 16 + rA) * 512 + kk * 32 + cswz), (void*)(&lA[cur ^ 1][blk * 512]));
        gload_lds16(Bp + ((size_t)(n0 + blk * 16 + rA) * 512 + kk * 32 + cswz), (void*)(&lB[cur ^ 1][blk * 512]));
      }
    }
    half8 af[4], bf[4];
    #pragma unroll
    for (int mf = 0; mf < 4; mf++)
      af[mf] = *(const half8*)&lA[cur][(wm * 64 + mf * 16 + (lane & 15)) * 32 + koffs];
    #pragma unroll
    for (int nf = 0; nf < 4; nf++)
      bf[nf] = *(const half8*)&lB[cur][(wn * 64 + nf * 16 + (lane & 15)) * 32 + koffs];
    #pragma unroll
    for (int mf = 0; mf < 4; mf++)
      #pragma unroll
      for (int nf = 0; nf < 4; nf++)
        acc[mf][nf] = __builtin_amdgcn_mfma_f32_16x16x32_f16(af[mf], bf[nf], acc[mf][nf], 0, 0, 0);
    if (kt == 15) {  // acc == Xh@W1T^T : persist XH (+bias) for the fixup path
      #pragma unroll
      for (int nf = 0; nf < 4; nf++) {
        int col = n0 + wn * 64 + nf * 16 + (lane & 15);
        float bv = bh[col];
        #pragma unroll
        for (int mf = 0; mf < 4; mf++) {
          int rbase = m0 + wm * 64 + mf * 16 + (lane >> 4) * 4;
          #pragma unroll
          for (int r = 0; r < 4; r++)
            XH[(size_t)(rbase + r) * 512 + col] = acc[mf][nf][r] + bv;
        }
      }
    }
    asm volatile("s_waitcnt vmcnt(0)" ::: "memory");
    __syncthreads();
    cur ^= 1;
  }
  #pragma unroll
  for (int tt = 0; tt < 2; tt++) {
    #pragma unroll
    for (int nf = 0; nf < 4; nf++) {
      int col = n0 + wn * 64 + nf * 16 + (lane & 15);
      float bv = bh[col];
      float cs = 0.f;
      #pragma unroll
      for (int mfp = 0; mfp < 2; mfp++) {
        int mf = tt * 2 + mfp;
        int rbase = m0 + wm * 64 + mf * 16 + (lane >> 4) * 4;
        #pragma unroll
        for (int r = 0; r < 4; r++) {
          float v = tanhf(acc[mf][nf][r] + bv);
          HH[(size_t)(rbase + r) * 512 + col] = (half_t)v;
          cs += v;
        }
      }
      cs += __shfl_xor(cs, 16, 64);
      cs += __shfl_xor(cs, 32, 64);
      if ((lane >> 4) == 0) {
        int t = (m0 >> 5) + wm * 2 + tt;
        HM[(size_t)t * 512 + col] = cs * (1.f / 32.f);
      }
    }
  }
}

// ---------------- NV[t] = hmean[t] @ Wv ----------------
__global__ __launch_bounds__(256) void kNVall(const float* __restrict__ HMm,
                                              const float* __restrict__ Wv,
                                              float* __restrict__ NV) {
  __shared__ float hm[512];
  int t = blockIdx.x;
  hm[threadIdx.x] = HMm[(size_t)t * 512 + threadIdx.x];
  hm[threadIdx.x + 256] = HMm[(size_t)t * 512 + threadIdx.x + 256];
  __syncthreads();
  for (int v = threadIdx.x; v < 512; v += 256) {
    float a = 0.f;
    #pragma unroll 4
    for (int i = 0; i < 512; i++) a += hm[i] * Wv[(size_t)i * 512 + v];
    NV[(size_t)t * 512 + v] = a;
  }
}

// ---------------- grid barrier (64 resident WGs) ----------------
__device__ __forceinline__ void gbar(int* bars, int id, int nwg) {
  __syncthreads();
  if (threadIdx.x == 0) {
    __hip_atomic_fetch_add(&bars[id], 1, __ATOMIC_ACQ_REL, __HIP_MEMORY_SCOPE_AGENT);
    while (__hip_atomic_load(&bars[id], __ATOMIC_ACQUIRE, __HIP_MEMORY_SCOPE_AGENT) < nwg)
      __builtin_amdgcn_s_sleep(4);
  }
  __syncthreads();
}

// ---------------- sequential fixup for steps that selected generated slots -----
__global__ __launch_bounds__(256) void kFixup(const int* __restrict__ DEP,
                                              int* __restrict__ bars,
                                              const float* __restrict__ XHm,
                                              const float* __restrict__ Wh,
                                              const float* __restrict__ Wv,
                                              const float* __restrict__ vals0,
                                              const float* __restrict__ WSo,
                                              const int* __restrict__ ISo,
                                              float* __restrict__ NV,
                                              float* __restrict__ RETR,
                                              float* __restrict__ HB,
                                              half_t* __restrict__ HHm) {
  __shared__ float rl[512];
  __shared__ float hm2[512];
  int w = blockIdx.x;
  int barid = 0;
  for (int t = 0; t < 64; t++) {
    if (DEP[t] == 0) continue;
    {
      int b = w >> 1, hf = w & 1;
      int c = hf * 256 + threadIdx.x;
      int row = t * 32 + b;
      float acc = 0.f;
      #pragma unroll
      for (int k2 = 0; k2 < 8; k2++) {
        int idx = ISo[(size_t)row * 8 + k2];
        float wv2 = WSo[(size_t)row * 8 + k2];
        const float* src = (idx < t) ? (NV + (size_t)idx * 512) : (vals0 + (size_t)idx * 512);
        acc += wv2 * src[c];
      }
      RETR[(size_t)b * 512 + c] = acc;
    }
    gbar(bars, barid++, 64);
    if (w < 32) {
      int b = w;
      rl[threadIdx.x] = RETR[(size_t)b * 512 + threadIdx.x];
      rl[threadIdx.x + 256] = RETR[(size_t)b * 512 + threadIdx.x + 256];
      __syncthreads();
      int row = t * 32 + b;
      for (int cc = 0; cc < 2; cc++) {
        int col = cc * 256 + threadIdx.x;
        float acc = 0.f;
        #pragma unroll 4
        for (int i = 0; i < 512; i++) acc += rl[i] * Wh[(size_t)(512 + i) * 512 + col];
        float h = tanhf(XHm[(size_t)row * 512 + col] + acc);
        HB[(size_t)b * 512 + col] = h;
        HHm[(size_t)row * 512 + col] = (half_t)h;
      }
    }
    gbar(bars, barid++, 64);
    if (w == 0) {
      for (int j = threadIdx.x; j < 512; j += 256) {
        float s = 0.f;
        for (int b = 0; b < 32; b++) s += HB[(size_t)b * 512 + j];
        hm2[j] = s * (1.f / 32.f);
      }
      __syncthreads();
      for (int v = threadIdx.x; v < 512; v += 256) {
        float a = 0.f;
        #pragma unroll 4
        for (int i = 0; i < 512; i++) a += hm2[i] * Wv[(size_t)i * 512 + v];
        NV[(size_t)t * 512 + v] = a;
      }
    }
    gbar(bars, barid++, 64);
  }
}

// ------- logits = HH @ WoutT^T + bout (fp16 MFMA, 2-phase prefetch, swizzle) ---
__global__ __launch_bounds__(256) void kLogits(const half_t* __restrict__ A,
                                               const half_t* __restrict__ Bm,
                                               const float* __restrict__ bout,
                                               float* __restrict__ C) {
  __shared__ half_t lA[2][128 * 32];
  __shared__ half_t lB[2][128 * 32];
  int lin = blockIdx.y * 250 + blockIdx.x;
  int swz = (lin & 7) * 500 + (lin >> 3);
  int m0 = (swz & 15) * 128;
  int n0 = (swz >> 4) * 128;
  int tid = threadIdx.x, wid = tid >> 6, lane = tid & 63;
  int wm = wid >> 1, wn = wid & 1;
  f32x4 acc[4][4];
  #pragma unroll
  for (int a2 = 0; a2 < 4; a2++)
    #pragma unroll
    for (int b2 = 0; b2 < 4; b2++) acc[a2][b2] = (f32x4){0.f, 0.f, 0.f, 0.f};

  int rA = lane >> 2;
  int cswz = ((lane & 3) ^ ((lane >> 3) & 3)) * 8;
  int koffs = (((lane >> 4) ^ ((lane >> 1) & 3))) * 8;
  // prologue: stage kt=0
  #pragma unroll
  for (int i2 = 0; i2 < 2; i2++) {
    int blk = wid * 2 + i2;
    gload_lds16(A + ((size_t)(m0 + blk * 16 + rA) * 512 + cswz), (void*)(&lA[0][blk * 512]));
    gload_lds16(Bm + ((size_t)(n0 + blk * 16 + rA) * 512 + cswz), (void*)(&lB[0][blk * 512]));
  }
  asm volatile("s_waitcnt vmcnt(0)" ::: "memory");
  __syncthreads();
  int cur = 0;
  for (int kt = 0; kt < 16; kt++) {
    if (kt < 15) {
      #pragma unroll
      for (int i2 = 0; i2 < 2; i2++) {
        int blk = wid * 2 + i2;
        gload_lds16(A + ((size_t)(m0 + blk * 16 + rA) * 512 + (kt + 1) * 32 + cswz), (void*)(&lA[cur ^ 1][blk * 512]));
        gload_lds16(Bm + ((size_t)(n0 + blk * 16 + rA) * 512 + (kt + 1) * 32 + cswz), (void*)(&lB[cur ^ 1][blk * 512]));
      }
    }
    half8 af[4], bf[4];
    #pragma unroll
    for (int mf = 0; mf < 4; mf++)
      af[mf] = *(const half8*)&lA[cur][(wm * 64 + mf * 16 + (lane & 15)) * 32 + koffs];
    #pragma unroll
    for (int nf = 0; nf < 4; nf++)
      bf[nf] = *(const half8*)&lB[cur][(wn * 64 + nf * 16 + (lane & 15)) * 32 + koffs];
    #pragma unroll
    for (int mf = 0; mf < 4; mf++)
      #pragma unroll
      for (int nf = 0; nf < 4; nf++)
        acc[mf][nf] = __builtin_amdgcn_mfma_f32_16x16x32_f16(af[mf], bf[nf], acc[mf][nf], 0, 0, 0);
    asm volatile("s_waitcnt vmcnt(0)" ::: "memory");
    __syncthreads();
    cur ^= 1;
  }
  #pragma unroll
  for (int nf = 0; nf < 4; nf++) {
    int col = n0 + wn * 64 + nf * 16 + (lane & 15);
    float bv = bout[col];
    #pragma unroll
    for (int mf = 0; mf < 4; mf++) {
      int rbase = m0 + wm * 64 + mf * 16 + (lane >> 4) * 4;
      #pragma unroll
      for (int r = 0; r < 4; r++)
        C[(size_t)(rbase + r) * 32000 + col] = acc[mf][nf][r] + bv;
    }
  }
}

extern "C" void kernel_launch(void* const* d_in, const int* in_sizes, int n_in,
                              void* d_out, int out_size, void* d_ws, size_t ws_size,
                              hipStream_t stream) {
  (void)in_sizes; (void)n_in; (void)out_size; (void)ws_size;
  const int*   tok   = (const int*)d_in[0];
  const float* emb   = (const float*)d_in[1];
  const float* Wq    = (const float*)d_in[2];
  const float* Wk    = (const float*)d_in[3];
  const float* Wv    = (const float*)d_in[4];
  const float* Wh    = (const float*)d_in[5];
  const float* bh    = (const float*)d_in[6];
  const float* Wout  = (const float*)d_in[7];
  const float* bout  = (const float*)d_in[8];
  const float* keys0 = (const float*)d_in[9];
  const float* vals0 = (const float*)d_in[10];
  float* Cout = (float*)d_out;

  char* ws = (char*)d_ws;
  size_t off = 0;
  auto alloc = [&](size_t bytes) -> char* {
    char* p = ws + off;
    off += (bytes + 255) & ~(size_t)255;
    return p;
  };
  half_t* WoutT = (half_t*)alloc(32768000);  // [32000][512] f16
  half_t* W1T   = (half_t*)alloc(524288);    // [512][512] f16
  half_t* W2T   = (half_t*)alloc(524288);    // [512][512] f16
  float*  X     = (float*) alloc(4194304);   // [2048][512]
  half_t* Xh    = (half_t*)alloc(2097152);   // [2048][512] f16
  double* Qd    = (double*)alloc(4194304);   // [2048][256]
  float*  Q32   = (float*) alloc(2097152);   // [2048][256] f32
  double* NKd   = (double*)alloc(131072);    // [64][256]
  double* XM    = (double*)alloc(262144);    // [64][512]
  float*  KC    = (float*) alloc(589824);    // [576][256] f32
  float*  Sb    = (float*) alloc(4718592);   // [2048][576] f32
  float*  XH    = (float*) alloc(4194304);   // [2048][512]
  float*  WSb   = (float*) alloc(65536);     // [2048][8]
  int*    ISb   = (int*)   alloc(65536);     // [2048][8]
  float*  NV    = (float*) alloc(131072);    // [64][512]
  half_t* R16   = (half_t*)alloc(2097152);   // [2048][512] f16
  half_t* HH    = (half_t*)alloc(2097152);   // [2048][512]
  float*  HM    = (float*) alloc(131072);    // [64][512]
  float*  RETR  = (float*) alloc(65536);     // [32][512]
  float*  HB    = (float*) alloc(65536);     // [32][512]
  int*    DEP   = (int*)   alloc(256);       // [64]
  int*    bars  = (int*)   alloc(1024);      // [256]

  kPrep<<<4128, 256, 0, stream>>>(Wout, WoutT, Wh, W1T, W2T);
  kGatherXM<<<576, 256, 0, stream>>>(tok, emb, X, Xh, XM, keys0, KC);
  kQ<<<512, 256, 0, stream>>>(X, Wq, Qd, Q32);
  kNK<<<64, 256, 0, stream>>>(XM, Wk, NKd, KC);
  kS<<<dim3(32, 9), 256, 0, stream>>>(Q32, KC, Sb);
  kTopk<<<512, 256, 0, stream>>>(Sb, Qd, NKd, keys0, WSb, ISb);
  kRetrDeps<<<2112, 256, 0, stream>>>(vals0, WSb, ISb, R16, DEP, bars);
  kFused<<<dim3(4, 16), 256, 0, stream>>>(Xh, R16, W1T, W2T, bh, XH, HH, HM);
  kNVall<<<64, 256, 0, stream>>>(HM, Wv, NV);
  kFixup<<<64, 256, 0, stream>>>(DEP, bars, XH, Wh, Wv, vals0, WSb, ISb, NV, RETR, HB, HH);
  kLogits<<<dim3(250, 16), 256, 0, stream>>>(HH, WoutT, bout, Cout);
}

// Round 7
// 460.127 us; speedup vs baseline: 1.3881x; 1.0423x over previous
//
#include <hip/hip_runtime.h>

typedef _Float16 half_t;
typedef _Float16 half8 __attribute__((ext_vector_type(8)));
typedef float f32x4 __attribute__((ext_vector_type(4)));

// dims: T=64 B=32 V=32000 E=512 H=512 N=512 DK=256 DV=512, TB=2048

__device__ __forceinline__ void gload_lds16(const void* g, void* l) {
  __builtin_amdgcn_global_load_lds((const __attribute__((address_space(1))) void*)g,
                                   (__attribute__((address_space(3))) void*)l, 16, 0, 0);
}

// ---- kPrep: bid<4000 Wout^T->f16; 4000..4127 Wh^T->W1T/W2T; 4128 zero DEP/bars
__global__ __launch_bounds__(256) void kPrep(const float* __restrict__ Wout,
                                             half_t* __restrict__ WoutT,
                                             const float* __restrict__ Wh,
                                             half_t* __restrict__ W1T,
                                             half_t* __restrict__ W2T,
                                             int* __restrict__ DEP,
                                             int* __restrict__ bars) {
  __shared__ half_t tile[64][68];
  int bid = blockIdx.x;
  if (bid < 4000) {
    int n0 = (bid % 500) * 64, k0 = (bid / 500) * 64;
    for (int p = 0; p < 4; p++) {
      int id = p * 256 + threadIdx.x;
      int k = id >> 4, nq = id & 15;
      float4 v = *(const float4*)&Wout[(size_t)(k0 + k) * 32000 + n0 + nq * 4];
      tile[nq * 4 + 0][k] = (half_t)v.x; tile[nq * 4 + 1][k] = (half_t)v.y;
      tile[nq * 4 + 2][k] = (half_t)v.z; tile[nq * 4 + 3][k] = (half_t)v.w;
    }
    __syncthreads();
    for (int p = 0; p < 2; p++) {
      int id = p * 256 + threadIdx.x;
      int n = id >> 3, kc = id & 7;
      half8 h = *(const half8*)&tile[n][kc * 8];
      *(half8*)&WoutT[(size_t)(n0 + n) * 512 + k0 + kc * 8] = h;
    }
  } else if (bid < 4128) {
    int id2 = bid - 4000;
    int n0 = (id2 & 7) * 64, k0 = (id2 >> 3) * 64;
    for (int p = 0; p < 16; p++) {
      int id = p * 256 + threadIdx.x;
      int kk = id >> 6, nn = id & 63;
      tile[nn][kk] = (half_t)Wh[(size_t)(k0 + kk) * 512 + n0 + nn];
    }
    __syncthreads();
    half_t* out = (k0 < 512) ? W1T : W2T;
    int kb = k0 & 511;
    for (int p = 0; p < 16; p++) {
      int id = p * 256 + threadIdx.x;
      int nn = id >> 6, kk = id & 63;
      out[(size_t)(n0 + nn) * 512 + kb + kk] = tile[nn][kk];
    }
  } else {
    if (threadIdx.x < 64) DEP[threadIdx.x] = 0;
    bars[threadIdx.x] = 0;
  }
}

// ---- kEmbed: per-t fp64 mean of emb rows -> NK (fp64 + f32) --------------------
__global__ __launch_bounds__(256) void kEmbed(const int* __restrict__ tok,
                                              const float* __restrict__ emb,
                                              const float* __restrict__ Wk,
                                              double* __restrict__ NKd,
                                              float* __restrict__ NKf) {
  __shared__ double xm[512];
  int t = blockIdx.x, c = threadIdx.x;
  double s0 = 0.0, s1 = 0.0;
  for (int b = 0; b < 32; b++) {
    const float* src = emb + (size_t)tok[t * 32 + b] * 512;
    s0 += (double)src[c]; s1 += (double)src[c + 256];
  }
  xm[c] = s0 * (1.0 / 32.0);
  xm[c + 256] = s1 * (1.0 / 32.0);
  __syncthreads();
  double a = 0;
  #pragma unroll 4
  for (int i = 0; i < 512; i++) a += xm[i] * (double)Wk[(size_t)i * 256 + c];
  NKd[(size_t)t * 256 + c] = a;
  NKf[(size_t)t * 256 + c] = (float)a;
}

// ---- kQG: gather emb rows (LDS) + Xh f16 + Q fp64/fp32, 4 rows per WG ----------
__global__ __launch_bounds__(256) void kQG(const int* __restrict__ tok,
                                           const float* __restrict__ emb,
                                           const float* __restrict__ Wq,
                                           double* __restrict__ Qd,
                                           float* __restrict__ Q32,
                                           half_t* __restrict__ Xh) {
  __shared__ float xs[4][512];
  int r0 = blockIdx.x * 4;
  int tid = threadIdx.x;
  for (int rr = 0; rr < 4; rr++) {
    int row = r0 + rr;
    const float* src = emb + (size_t)tok[row] * 512;
    float v0 = src[tid], v1 = src[tid + 256];
    xs[rr][tid] = v0; xs[rr][tid + 256] = v1;
    Xh[(size_t)row * 512 + tid] = (half_t)v0;
    Xh[(size_t)row * 512 + tid + 256] = (half_t)v1;
  }
  __syncthreads();
  int d = tid;
  double a0 = 0, a1 = 0, a2 = 0, a3 = 0;
  #pragma unroll 4
  for (int i = 0; i < 512; i++) {
    double w = (double)Wq[(size_t)i * 256 + d];
    a0 += (double)xs[0][i] * w; a1 += (double)xs[1][i] * w;
    a2 += (double)xs[2][i] * w; a3 += (double)xs[3][i] * w;
  }
  Qd[(size_t)(r0 + 0) * 256 + d] = a0; Qd[(size_t)(r0 + 1) * 256 + d] = a1;
  Qd[(size_t)(r0 + 2) * 256 + d] = a2; Qd[(size_t)(r0 + 3) * 256 + d] = a3;
  Q32[(size_t)(r0 + 0) * 256 + d] = (float)a0; Q32[(size_t)(r0 + 1) * 256 + d] = (float)a1;
  Q32[(size_t)(r0 + 2) * 256 + d] = (float)a2; Q32[(size_t)(r0 + 3) * 256 + d] = (float)a3;
}

// ---- S[2048][576] = Q32 @ concat(keys0,NKf)^T (fp32 tiled GEMM) ----------------
__global__ __launch_bounds__(256) void kS(const float* __restrict__ Q32,
                                          const float* __restrict__ keys0,
                                          const float* __restrict__ NKf,
                                          float* __restrict__ S) {
  __shared__ float As[32][68];
  __shared__ float Bs[32][68];
  int m0 = blockIdx.x * 64, n0 = blockIdx.y * 64;
  int tid = threadIdx.x;
  int tx = tid & 15, ty = tid >> 4;
  float acc[4][4];
  #pragma unroll
  for (int i = 0; i < 4; i++)
    #pragma unroll
    for (int j = 0; j < 4; j++) acc[i][j] = 0.f;
  for (int kc = 0; kc < 256; kc += 32) {
    __syncthreads();
    #pragma unroll
    for (int p = 0; p < 8; p++) {
      int idx = p * 256 + tid;
      int k = idx & 31, m = idx >> 5;
      As[k][m] = Q32[(size_t)(m0 + m) * 256 + kc + k];
      int n = n0 + m;
      Bs[k][m] = (n < 512) ? keys0[(size_t)n * 256 + kc + k]
                           : NKf[(size_t)(n - 512) * 256 + kc + k];
    }
    __syncthreads();
    #pragma unroll
    for (int k = 0; k < 32; k++) {
      float4 a = *(const float4*)&As[k][ty * 4];
      float4 b = *(const float4*)&Bs[k][tx * 4];
      acc[0][0] += a.x * b.x; acc[0][1] += a.x * b.y; acc[0][2] += a.x * b.z; acc[0][3] += a.x * b.w;
      acc[1][0] += a.y * b.x; acc[1][1] += a.y * b.y; acc[1][2] += a.y * b.z; acc[1][3] += a.y * b.w;
      acc[2][0] += a.z * b.x; acc[2][1] += a.z * b.y; acc[2][2] += a.z * b.z; acc[2][3] += a.z * b.w;
      acc[3][0] += a.w * b.x; acc[3][1] += a.w * b.y; acc[3][2] += a.w * b.z; acc[3][3] += a.w * b.w;
    }
  }
  #pragma unroll
  for (int i = 0; i < 4; i++) {
    float4 o = {acc[i][0], acc[i][1], acc[i][2], acc[i][3]};
    *(float4*)&S[(size_t)(m0 + ty * 4 + i) * 576 + n0 + tx * 4] = o;
  }
}

// ---- per-row top-16 -> fp64 rescore -> top-8 + softmax + R16 + DEP -------------
__global__ __launch_bounds__(256) void kTopkRetr(const float* __restrict__ S,
                                                 const double* __restrict__ Qd,
                                                 const double* __restrict__ NKd,
                                                 const float* __restrict__ keys0,
                                                 const float* __restrict__ vals0,
                                                 float* __restrict__ WSo,
                                                 int* __restrict__ ISo,
                                                 half_t* __restrict__ R16,
                                                 int* __restrict__ DEP) {
  __shared__ float wls[4][8];
  __shared__ int ils[4][8];
  __shared__ int depf;
  int tid = threadIdx.x;
  if (tid == 0) depf = 0;
  __syncthreads();
  int r0b = blockIdx.x * 4;
  int wv = tid >> 6, lane = tid & 63;
  int row = r0b + wv;
  int t = row >> 5;
  const float* Srow = S + (size_t)row * 576;
  float v[8];
  #pragma unroll
  for (int j = 0; j < 8; j++) v[j] = Srow[j * 64 + lane];
  if (lane < t) v[0] = Srow[512 + lane];   // slot<t holds the generated key
  int ci[16];
  #pragma unroll
  for (int it = 0; it < 16; it++) {
    float bv = -1e30f; int bi = 0x7fffffff;
    #pragma unroll
    for (int j = 0; j < 8; j++) {
      int ii = j * 64 + lane;
      if (v[j] > bv || (v[j] == bv && ii < bi)) { bv = v[j]; bi = ii; }
    }
    #pragma unroll
    for (int s = 32; s > 0; s >>= 1) {
      float ov = __shfl_xor(bv, s, 64);
      int oi = __shfl_xor(bi, s, 64);
      if (ov > bv || (ov == bv && oi < bi)) { bv = ov; bi = oi; }
    }
    ci[it] = bi;
    #pragma unroll
    for (int j = 0; j < 8; j++)
      if (j * 64 + lane == bi) v[j] = -1e30f;
  }
  // fp64 rescore of the 16 candidates
  const double* qrow = Qd + (size_t)row * 256 + lane * 4;
  double q0 = qrow[0], q1 = qrow[1], q2 = qrow[2], q3 = qrow[3];
  double dv[16];
  #pragma unroll
  for (int c = 0; c < 16; c++) {
    int idx = ci[c];
    double p;
    if (idx < t) {
      const double* kr = NKd + (size_t)idx * 256 + lane * 4;
      p = q0 * kr[0] + q1 * kr[1] + q2 * kr[2] + q3 * kr[3];
    } else {
      const float* kr = keys0 + (size_t)idx * 256 + lane * 4;
      p = q0 * (double)kr[0] + q1 * (double)kr[1] + q2 * (double)kr[2] + q3 * (double)kr[3];
    }
    #pragma unroll
    for (int s = 32; s > 0; s >>= 1) p += __shfl_xor(p, s, 64);
    dv[c] = p * 0.0625;
  }
  double tv[8]; int ti[8];
  #pragma unroll
  for (int it = 0; it < 8; it++) {
    double bv = -1e300; int bi = 0x7fffffff;
    #pragma unroll
    for (int c = 0; c < 16; c++)
      if (dv[c] > bv || (dv[c] == bv && ci[c] < bi)) { bv = dv[c]; bi = ci[c]; }
    tv[it] = bv; ti[it] = bi;
    #pragma unroll
    for (int c = 0; c < 16; c++)
      if (ci[c] == bi) dv[c] = -1e300;
  }
  if (lane == 0) {
    double m = tv[0], ev[8], Z = 0;
    #pragma unroll
    for (int i2 = 0; i2 < 8; i2++) { ev[i2] = exp(tv[i2] - m); Z += ev[i2]; }
    double inv = 1.0 / Z;
    int dep = 0;
    #pragma unroll
    for (int i2 = 0; i2 < 8; i2++) {
      float w = (float)(ev[i2] * inv);
      WSo[(size_t)row * 8 + i2] = w;
      ISo[(size_t)row * 8 + i2] = ti[i2];
      wls[wv][i2] = w; ils[wv][i2] = ti[i2];
      if (ti[i2] < t) dep = 1;
    }
    if (dep) atomicOr(&depf, 1);
  }
  __syncthreads();
  if (tid == 0 && depf) atomicOr(&DEP[t], 1);
  // fast-path retrieved -> fp16
  for (int rr = 0; rr < 4; rr++) {
    float a0 = 0.f, a1 = 0.f;
    #pragma unroll
    for (int k2 = 0; k2 < 8; k2++) {
      const float* src = vals0 + (size_t)ils[rr][k2] * 512;
      a0 += wls[rr][k2] * src[tid];
      a1 += wls[rr][k2] * src[tid + 256];
    }
    R16[(size_t)(r0b + rr) * 512 + tid] = (half_t)a0;
    R16[(size_t)(r0b + rr) * 512 + tid + 256] = (half_t)a1;
  }
}

// ---- grid barrier (64 resident WGs) --------------------------------------------
__device__ __forceinline__ void gbar(int* bars, int id, int nwg) {
  __syncthreads();
  if (threadIdx.x == 0) {
    __hip_atomic_fetch_add(&bars[id], 1, __ATOMIC_ACQ_REL, __HIP_MEMORY_SCOPE_AGENT);
    while (__hip_atomic_load(&bars[id], __ATOMIC_ACQUIRE, __HIP_MEMORY_SCOPE_AGENT) < nwg)
      __builtin_amdgcn_s_sleep(4);
  }
  __syncthreads();
}

// ---- fused: concat-GEMM(T4 pipeline) + XH + HH + HM + NV + fixup ---------------
__global__ __launch_bounds__(256) void kFusedAll(
    const half_t* __restrict__ Xh, const half_t* __restrict__ R16,
    const half_t* __restrict__ W1T, const half_t* __restrict__ W2T,
    const float* __restrict__ bh, const float* __restrict__ Wv,
    const float* __restrict__ Wh, const float* __restrict__ vals0,
    const float* __restrict__ WSo, const int* __restrict__ ISo,
    const int* __restrict__ DEP, int* __restrict__ bars,
    float* __restrict__ XH, half_t* __restrict__ HH, float* __restrict__ HM,
    float* __restrict__ NV, float* __restrict__ RETR, float* __restrict__ HB) {
  __shared__ half_t lA[3][128 * 32];
  __shared__ half_t lB[3][128 * 32];
  __shared__ float hmld[512];
  __shared__ float rl[512];
  __shared__ float hm2[512];
  __shared__ int depl[64];
  int w = blockIdx.x;
  int n0 = (w & 3) * 128, m0 = (w >> 2) * 128;
  int tid = threadIdx.x, wid = tid >> 6, lane = tid & 63;
  int wm = wid >> 1, wn = wid & 1;
  f32x4 acc[4][4];
  #pragma unroll
  for (int a2 = 0; a2 < 4; a2++)
    #pragma unroll
    for (int b2 = 0; b2 < 4; b2++) acc[a2][b2] = (f32x4){0.f, 0.f, 0.f, 0.f};
  int rA = lane >> 2;
  int cswz = ((lane & 3) ^ ((lane >> 3) & 3)) * 8;
  int koffs = (((lane >> 4) ^ ((lane >> 1) & 3))) * 8;
  auto issue = [&](int j, int buf) {
    const half_t* Ap = (j < 16) ? Xh : R16;
    const half_t* Bp = (j < 16) ? W1T : W2T;
    int kk = j & 15;
    #pragma unroll
    for (int i2 = 0; i2 < 2; i2++) {
      int blk = wid * 2 + i2;
      gload_lds16(Ap + ((size_t)(m0 + blk * 16 + rA) * 512 + kk * 32 + cswz), (void*)(&lA[buf][blk * 512]));
      gload_lds16(Bp + ((size_t)(n0 + blk * 16 + rA) * 512 + kk * 32 + cswz), (void*)(&lB[buf][blk * 512]));
    }
  };
  issue(0, 0); issue(1, 1);
  for (int kt = 0; kt < 32; kt++) {
    if (kt < 31) asm volatile("s_waitcnt vmcnt(4)\n\ts_barrier" ::: "memory");
    else         asm volatile("s_waitcnt vmcnt(0)\n\ts_barrier" ::: "memory");
    int cur = kt % 3;
    half8 af[4], bf[4];
    #pragma unroll
    for (int mf = 0; mf < 4; mf++)
      af[mf] = *(const half8*)&lA[cur][(wm * 64 + mf * 16 + (lane & 15)) * 32 + koffs];
    #pragma unroll
    for (int nf = 0; nf < 4; nf++)
      bf[nf] = *(const half8*)&lB[cur][(wn * 64 + nf * 16 + (lane & 15)) * 32 + koffs];
    if (kt < 30) issue(kt + 2, (kt + 2) % 3);
    #pragma unroll
    for (int mf = 0; mf < 4; mf++)
      #pragma unroll
      for (int nf = 0; nf < 4; nf++)
        acc[mf][nf] = __builtin_amdgcn_mfma_f32_16x16x32_f16(af[mf], bf[nf], acc[mf][nf], 0, 0, 0);
    if (kt == 15) {  // acc == Xh@W1T^T : persist XH (+bias) for the fixup path
      #pragma unroll
      for (int nf = 0; nf < 4; nf++) {
        int col = n0 + wn * 64 + nf * 16 + (lane & 15);
        float bv = bh[col];
        #pragma unroll
        for (int mf = 0; mf < 4; mf++) {
          int rbase = m0 + wm * 64 + mf * 16 + (lane >> 4) * 4;
          #pragma unroll
          for (int r = 0; r < 4; r++)
            XH[(size_t)(rbase + r) * 512 + col] = acc[mf][nf][r] + bv;
        }
      }
    }
  }
  // epilogue: tanh + HH + per-t column means
  #pragma unroll
  for (int tt = 0; tt < 2; tt++) {
    #pragma unroll
    for (int nf = 0; nf < 4; nf++) {
      int col = n0 + wn * 64 + nf * 16 + (lane & 15);
      float bv = bh[col];
      float cs = 0.f;
      #pragma unroll
      for (int mfp = 0; mfp < 2; mfp++) {
        int mf = tt * 2 + mfp;
        int rbase = m0 + wm * 64 + mf * 16 + (lane >> 4) * 4;
        #pragma unroll
        for (int r = 0; r < 4; r++) {
          float v = tanhf(acc[mf][nf][r] + bv);
          HH[(size_t)(rbase + r) * 512 + col] = (half_t)v;
          cs += v;
        }
      }
      cs += __shfl_xor(cs, 16, 64);
      cs += __shfl_xor(cs, 32, 64);
      if ((lane >> 4) == 0) {
        int t = (m0 >> 5) + wm * 2 + tt;
        HM[(size_t)t * 512 + col] = cs * (1.f / 32.f);
      }
    }
  }
  gbar(bars, 0, 64);
  // NV[w] = HM[w] @ Wv
  hmld[tid] = HM[(size_t)w * 512 + tid];
  hmld[tid + 256] = HM[(size_t)w * 512 + tid + 256];
  __syncthreads();
  for (int v = tid; v < 512; v += 256) {
    float a = 0.f;
    #pragma unroll 4
    for (int i = 0; i < 512; i++) a += hmld[i] * Wv[(size_t)i * 512 + v];
    NV[(size_t)w * 512 + v] = a;
  }
  gbar(bars, 1, 64);
  if (tid < 64) depl[tid] = DEP[tid];
  __syncthreads();
  int barid = 2;
  for (int t = 0; t < 64; t++) {
    if (depl[t] == 0) continue;
    {  // phase A: retrieved with NV for idx<t
      int b = w >> 1, hf = w & 1;
      int c = hf * 256 + tid;
      int row = t * 32 + b;
      float a = 0.f;
      #pragma unroll
      for (int k2 = 0; k2 < 8; k2++) {
        int idx = ISo[(size_t)row * 8 + k2];
        float wv2 = WSo[(size_t)row * 8 + k2];
        const float* src = (idx < t) ? (NV + (size_t)idx * 512) : (vals0 + (size_t)idx * 512);
        a += wv2 * src[c];
      }
      RETR[(size_t)b * 512 + c] = a;
    }
    gbar(bars, barid++, 64);
    if (w < 32) {  // phase B: h row b
      int b = w;
      rl[tid] = RETR[(size_t)b * 512 + tid];
      rl[tid + 256] = RETR[(size_t)b * 512 + tid + 256];
      __syncthreads();
      int row = t * 32 + b;
      for (int cc = 0; cc < 2; cc++) {
        int col = cc * 256 + tid;
        float a = 0.f;
        #pragma unroll 4
        for (int i = 0; i < 512; i++) a += rl[i] * Wh[(size_t)(512 + i) * 512 + col];
        float h = tanhf(XH[(size_t)row * 512 + col] + a);
        HB[(size_t)b * 512 + col] = h;
        HH[(size_t)row * 512 + col] = (half_t)h;
      }
    }
    gbar(bars, barid++, 64);
    if (w == 0) {  // phase C: hmean + NV[t]
      for (int j = tid; j < 512; j += 256) {
        float s = 0.f;
        for (int b = 0; b < 32; b++) s += HB[(size_t)b * 512 + j];
        hm2[j] = s * (1.f / 32.f);
      }
      __syncthreads();
      for (int v = tid; v < 512; v += 256) {
        float a = 0.f;
        #pragma unroll 4
        for (int i = 0; i < 512; i++) a += hm2[i] * Wv[(size_t)i * 512 + v];
        NV[(size_t)t * 512 + v] = a;
      }
    }
    gbar(bars, barid++, 64);
  }
}

// ---- logits = HH @ WoutT^T + bout (fp16 MFMA, T4 3-buf pipeline, swizzle) ------
__global__ __launch_bounds__(256) void kLogits(const half_t* __restrict__ A,
                                               const half_t* __restrict__ Bm,
                                               const float* __restrict__ bout,
                                               float* __restrict__ C) {
  __shared__ half_t lA[3][128 * 32];
  __shared__ half_t lB[3][128 * 32];
  int lin = blockIdx.y * 250 + blockIdx.x;
  int swz = (lin & 7) * 500 + (lin >> 3);
  int m0 = (swz & 15) * 128;
  int n0 = (swz >> 4) * 128;
  int tid = threadIdx.x, wid = tid >> 6, lane = tid & 63;
  int wm = wid >> 1, wn = wid & 1;
  f32x4 acc[4][4];
  #pragma unroll
  for (int a2 = 0; a2 < 4; a2++)
    #pragma unroll
    for (int b2 = 0; b2 < 4; b2++) acc[a2][b2] = (f32x4){0.f, 0.f, 0.f, 0.f};
  int rA = lane >> 2;
  int cswz = ((lane & 3) ^ ((lane >> 3) & 3)) * 8;
  int koffs = (((lane >> 4) ^ ((lane >> 1) & 3))) * 8;
  auto issue = [&](int j, int buf) {
    #pragma unroll
    for (int i2 = 0; i2 < 2; i2++) {
      int blk = wid * 2 + i2;
      gload_lds16(A + ((size_t)(m0 + blk * 16 + rA) * 512 + j * 32 + cswz), (void*)(&lA[buf][blk * 512]));
      gload_lds16(Bm + ((size_t)(n0 + blk * 16 + rA) * 512 + j * 32 + cswz), (void*)(&lB[buf][blk * 512]));
    }
  };
  issue(0, 0); issue(1, 1);
  for (int kt = 0; kt < 16; kt++) {
    if (kt < 15) asm volatile("s_waitcnt vmcnt(4)\n\ts_barrier" ::: "memory");
    else         asm volatile("s_waitcnt vmcnt(0)\n\ts_barrier" ::: "memory");
    int cur = kt % 3;
    half8 af[4], bf[4];
    #pragma unroll
    for (int mf = 0; mf < 4; mf++)
      af[mf] = *(const half8*)&lA[cur][(wm * 64 + mf * 16 + (lane & 15)) * 32 + koffs];
    #pragma unroll
    for (int nf = 0; nf < 4; nf++)
      bf[nf] = *(const half8*)&lB[cur][(wn * 64 + nf * 16 + (lane & 15)) * 32 + koffs];
    if (kt < 14) issue(kt + 2, (kt + 2) % 3);
    #pragma unroll
    for (int mf = 0; mf < 4; mf++)
      #pragma unroll
      for (int nf = 0; nf < 4; nf++)
        acc[mf][nf] = __builtin_amdgcn_mfma_f32_16x16x32_f16(af[mf], bf[nf], acc[mf][nf], 0, 0, 0);
  }
  #pragma unroll
  for (int nf = 0; nf < 4; nf++) {
    int col = n0 + wn * 64 + nf * 16 + (lane & 15);
    float bv = bout[col];
    #pragma unroll
    for (int mf = 0; mf < 4; mf++) {
      int rbase = m0 + wm * 64 + mf * 16 + (lane >> 4) * 4;
      #pragma unroll
      for (int r = 0; r < 4; r++)
        C[(size_t)(rbase + r) * 32000 + col] = acc[mf][nf][r] + bv;
    }
  }
}

extern "C" void kernel_launch(void* const* d_in, const int* in_sizes, int n_in,
                              void* d_out, int out_size, void* d_ws, size_t ws_size,
                              hipStream_t stream) {
  (void)in_sizes; (void)n_in; (void)out_size; (void)ws_size;
  const int*   tok   = (const int*)d_in[0];
  const float* emb   = (const float*)d_in[1];
  const float* Wq    = (const float*)d_in[2];
  const float* Wk    = (const float*)d_in[3];
  const float* Wv    = (const float*)d_in[4];
  const float* Wh    = (const float*)d_in[5];
  const float* bh    = (const float*)d_in[6];
  const float* Wout  = (const float*)d_in[7];
  const float* bout  = (const float*)d_in[8];
  const float* keys0 = (const float*)d_in[9];
  const float* vals0 = (const float*)d_in[10];
  float* Cout = (float*)d_out;

  char* ws = (char*)d_ws;
  size_t off = 0;
  auto alloc = [&](size_t bytes) -> char* {
    char* p = ws + off;
    off += (bytes + 255) & ~(size_t)255;
    return p;
  };
  half_t* WoutT = (half_t*)alloc(32768000);  // [32000][512] f16
  half_t* W1T   = (half_t*)alloc(524288);    // [512][512] f16
  half_t* W2T   = (half_t*)alloc(524288);    // [512][512] f16
  half_t* Xh    = (half_t*)alloc(2097152);   // [2048][512] f16
  double* Qd    = (double*)alloc(4194304);   // [2048][256]
  float*  Q32   = (float*) alloc(2097152);   // [2048][256] f32
  double* NKd   = (double*)alloc(131072);    // [64][256]
  float*  NKf   = (float*) alloc(65536);     // [64][256] f32
  float*  Sb    = (float*) alloc(4718592);   // [2048][576] f32
  float*  XH    = (float*) alloc(4194304);   // [2048][512]
  float*  WSb   = (float*) alloc(65536);     // [2048][8]
  int*    ISb   = (int*)   alloc(65536);     // [2048][8]
  float*  NV    = (float*) alloc(131072);    // [64][512]
  half_t* R16   = (half_t*)alloc(2097152);   // [2048][512] f16
  half_t* HH    = (half_t*)alloc(2097152);   // [2048][512]
  float*  HM    = (float*) alloc(131072);    // [64][512]
  float*  RETR  = (float*) alloc(65536);     // [32][512]
  float*  HB    = (float*) alloc(65536);     // [32][512]
  int*    DEP   = (int*)   alloc(256);       // [64]
  int*    bars  = (int*)   alloc(1024);      // [256]

  kPrep<<<4129, 256, 0, stream>>>(Wout, WoutT, Wh, W1T, W2T, DEP, bars);
  kEmbed<<<64, 256, 0, stream>>>(tok, emb, Wk, NKd, NKf);
  kQG<<<512, 256, 0, stream>>>(tok, emb, Wq, Qd, Q32, Xh);
  kS<<<dim3(32, 9), 256, 0, stream>>>(Q32, keys0, NKf, Sb);
  kTopkRetr<<<512, 256, 0, stream>>>(Sb, Qd, NKd, keys0, vals0, WSb, ISb, R16, DEP);
  kFusedAll<<<64, 256, 0, stream>>>(Xh, R16, W1T, W2T, bh, Wv, Wh, vals0,
                                    WSb, ISb, DEP, bars, XH, HH, HM, NV, RETR, HB);
  kLogits<<<dim3(250, 16), 256, 0, stream>>>(HH, WoutT, bout, Cout);
}